// Round 15
// baseline (841.909 us; speedup 1.0000x reference)
//
#include <hip/hip_runtime.h>
#include <hip/hip_bf16.h>
#include <stdint.h>

typedef __bf16 bf16;
typedef __bf16 bf16x8 __attribute__((ext_vector_type(8)));
typedef float f32x4 __attribute__((ext_vector_type(4)));

#define AS1 __attribute__((address_space(1)))
#define AS3 __attribute__((address_space(3)))

// B=4, S=256, H=12, DH=64(pad 128), D=768, FD=2048, FU=2048
// Inputs fp32 + int32 mask. OUTPUT IS FLOAT32 (reference returns fp32!) —
// rounds 3-14 wrote bf16 into a float* buffer; the fp32 readback of packed
// bf16 pairs produced the decorrelated-but-right-distribution signature.
// K segment per head = 768 (PX/M part) + 2048 (PU/V part) = 2816

__device__ __forceinline__ void gld16(const bf16* g, bf16* l) {
  __builtin_amdgcn_global_load_lds((AS1 void*)g, (AS3 void*)l, 16, 0, 0);
}

// sentinel: absmax ~2^20 signals "input size multiset unexpected"
__global__ void k_sentinel(float* __restrict__ out) {
  int i = blockIdx.x * 256 + threadIdx.x;
  if (i < 2097152) out[i] = 1048576.0f;
}

// ---------------- prep kernels ----------------

__global__ void k_invln(const float* __restrict__ ln, float* __restrict__ invln) {
  int i = blockIdx.x * 256 + threadIdx.x;
  if (i < 1024) invln[i] = 1.0f / ln[i];
}

__global__ void k_cast(const float* __restrict__ s, bf16* __restrict__ d, int n) {
  int i = blockIdx.x * 256 + threadIdx.x;
  if (i < n) d[i] = (bf16)s[i];
}

// WOb[h][r<128][o<768], rows >=64 zero-padded
__global__ void k_WO(const float* __restrict__ W_O, bf16* __restrict__ WOb) {
  int i = blockIdx.x * 256 + threadIdx.x;           // 12*128*768
  int o = i % 768, r = (i / 768) & 127, h = i / (768 * 128);
  WOb[i] = (r < 64) ? (bf16)W_O[(long)(h * 64 + r) * 768 + o] : (bf16)0.0f;
}

// WVb[h][m<768][k<128], k>=64 zero-padded
__global__ void k_WV(const float* __restrict__ W_V, bf16* __restrict__ WVb) {
  int i = blockIdx.x * 256 + threadIdx.x;           // 12*768*128
  int k = i & 127, m = (i / 128) % 768, h = i / (128 * 768);
  WVb[i] = (k < 64) ? (bf16)W_V[(long)(h * 768 + m) * 64 + k] : (bf16)0.0f;
}

// updWt[u][i] = up_dec_W[i][u]
__global__ void k_updWt(const float* __restrict__ u, bf16* __restrict__ d) {
  int i = blockIdx.x * 256 + threadIdx.x;           // 2048*768
  int ii = i % 768, uu = i / 768;
  d[i] = (bf16)u[(long)ii * 2048 + uu];
}

// Xt[b][i][s] = resid[b][s][i] / ln
__global__ void k_Xt(const float* __restrict__ resid, const float* __restrict__ invln,
                     bf16* __restrict__ Xt) {
  int i = blockIdx.x * 256 + threadIdx.x;           // 4*768*256
  int s = i & 255, d = (i >> 8) % 768, b = i / (768 * 256);
  int bs = b * 256 + s;
  Xt[i] = (bf16)(resid[(long)bs * 768 + d] * invln[bs]);
}

// Ut[b][u][s] = pruned[b][s][u] / ln
__global__ void k_Ut(const float* __restrict__ pr, const float* __restrict__ invln,
                     bf16* __restrict__ Ut) {
  int i = blockIdx.x * 256 + threadIdx.x;           // 4*2048*256
  int s = i & 255, u = (i >> 8) & 2047, b = i / (2048 * 256);
  int bs = b * 256 + s;
  Ut[i] = (bf16)(pr[(long)bs * 2048 + u] * invln[bs]);
}

// ---------------- bias chain (fp32, block-parallel) ----------------

__device__ __forceinline__ float blk_reduce(float s) {
  __shared__ float red[256];
  red[threadIdx.x] = s; __syncthreads();
  for (int o = 128; o > 0; o >>= 1) {
    if ((int)threadIdx.x < o) red[threadIdx.x] += red[threadIdx.x + o];
    __syncthreads();
  }
  float r = red[0]; __syncthreads();
  return r;
}

// t_hk[h*64+k] = sum_m W_V[h,m,k]*up_b[m]   (768 blocks)
__global__ void k_bias_t(const float* __restrict__ W_V, const float* __restrict__ up_b,
                         float* __restrict__ t_hk) {
  int j = blockIdx.x, h = j >> 6, k = j & 63;
  float s = 0.f;
  for (int m = threadIdx.x; m < 768; m += 256)
    s += W_V[((long)(h * 768 + m)) * 64 + k] * up_b[m];
  float r = blk_reduce(s);
  if (threadIdx.x == 0) t_hk[j] = r;
}

// w[d] = sum_j W_O_flat[j*768+d]*t_hk[j]   (768 blocks)
__global__ void k_bias_w(const float* __restrict__ W_O, const float* __restrict__ t_hk,
                         float* __restrict__ w) {
  int d = blockIdx.x;
  float s = 0.f;
  for (int j = threadIdx.x; j < 768; j += 256)
    s += W_O[(long)j * 768 + d] * t_hk[j];
  float r = blk_reduce(s);
  if (threadIdx.x == 0) w[d] = r;
}

// c0[f] = enc_b[f] - enc_W[f,:].b_dec ;  c1[f] = enc_W[f,:].w   (2048 blocks)
__global__ void k_bias_c(const float* __restrict__ enc_W, const float* __restrict__ enc_b,
                         const float* __restrict__ b_dec, const float* __restrict__ w,
                         float* __restrict__ c0, float* __restrict__ c1) {
  int f = blockIdx.x;
  float s0 = 0.f, s1 = 0.f;
  for (int d = threadIdx.x; d < 768; d += 256) {
    float e = enc_W[(long)f * 768 + d];
    s0 += e * b_dec[d];
    s1 += e * w[d];
  }
  float r0 = blk_reduce(s0);
  float r1 = blk_reduce(s1);
  if (threadIdx.x == 0) { c0[f] = enc_b[f] - r0; c1[f] = r1; }
}

// ---------------- GEMM (BT form: C[m,n] = sum_k A[m,k]*B[n,k]) ----------------
// mode 0: bf16 store; mode 1: *= mask, bf16 store;
// mode 2: split-K fp32 overwrite; mode 3: split-K fp32 read-accumulate
__global__ __launch_bounds__(256)
void gemm_bt(const bf16* __restrict__ A, const bf16* __restrict__ B, void* __restrict__ Cv,
             int M, int N, int K,
             long lda, long ldb, long ldc,
             int batchH,
             long sa_b, long sa_h, long sb_b, long sb_h, long sc_b, long sc_h,
             int mode, int kChunk,
             const int* __restrict__ mask, long mask_ld)
{
  __shared__ __align__(16) bf16 Asm[128 * 32];
  __shared__ __align__(16) bf16 Bsm[128 * 32];

  const int t = threadIdx.x;
  const int m0 = blockIdx.y * 128;
  const int n0 = blockIdx.x * 128;

  long aoff, boff, coff;
  int k0, k1;
  if (mode >= 2) {
    int z = blockIdx.z;
    aoff = 0; boff = 0;
    coff = (long)z * (long)M * ldc;
    k0 = z * kChunk; k1 = k0 + kChunk; if (k1 > K) k1 = K;
  } else {
    int z = blockIdx.z;
    int bb = z / batchH, hh = z - bb * batchH;
    aoff = (long)bb * sa_b + (long)hh * sa_h;
    boff = (long)bb * sb_b + (long)hh * sb_h;
    coff = (long)bb * sc_b + (long)hh * sc_h;
    k0 = 0; k1 = K;
  }

  const bf16* Ab = A + aoff + (long)m0 * lda;
  const bf16* Bb = B + boff + (long)n0 * ldb;

  const int r0 = t >> 2;           // 0..63
  const int kk = (t & 3) << 3;     // 0,8,16,24

  const int L = t & 63, w = t >> 6;
  const int wm = (w & 1) * 64, wn = (w >> 1) * 64;
  const int r16 = L & 15, q = L >> 4;

  f32x4 acc[4][4];
#pragma unroll
  for (int i = 0; i < 4; i++)
#pragma unroll
    for (int j = 0; j < 4; j++) acc[i][j] = (f32x4){0.f, 0.f, 0.f, 0.f};

  for (int kt = k0; kt < k1; kt += 32) {
    gld16(Ab + (long)r0 * lda + (kt + kk),        &Asm[t * 8]);
    gld16(Ab + (long)(r0 + 64) * lda + (kt + kk), &Asm[2048 + t * 8]);
    gld16(Bb + (long)r0 * ldb + (kt + kk),        &Bsm[t * 8]);
    gld16(Bb + (long)(r0 + 64) * ldb + (kt + kk), &Bsm[2048 + t * 8]);
    __syncthreads();

    bf16x8 af[4], bfr[4];
#pragma unroll
    for (int i = 0; i < 4; i++) {
      af[i]  = *(const bf16x8*)&Asm[(wm + i * 16 + r16) * 32 + q * 8];
      bfr[i] = *(const bf16x8*)&Bsm[(wn + i * 16 + r16) * 32 + q * 8];
    }
#pragma unroll
    for (int mi = 0; mi < 4; mi++)
#pragma unroll
      for (int ni = 0; ni < 4; ni++)
        acc[mi][ni] = __builtin_amdgcn_mfma_f32_16x16x32_bf16(af[mi], bfr[ni], acc[mi][ni], 0, 0, 0);
    __syncthreads();
  }

  if (mode >= 2) {
    float* C = (float*)Cv;
#pragma unroll
    for (int mi = 0; mi < 4; mi++)
#pragma unroll
      for (int ni = 0; ni < 4; ni++)
#pragma unroll
        for (int r = 0; r < 4; r++) {
          int gm = m0 + wm + mi * 16 + q * 4 + r;
          int gn = n0 + wn + ni * 16 + r16;
          long idx = coff + (long)gm * ldc + gn;
          float v = acc[mi][ni][r];
          if (mode == 3) v += C[idx];
          C[idx] = v;
        }
  } else {
    bf16* C = (bf16*)Cv;
#pragma unroll
    for (int mi = 0; mi < 4; mi++)
#pragma unroll
      for (int ni = 0; ni < 4; ni++)
#pragma unroll
        for (int r = 0; r < 4; r++) {
          int gm = m0 + wm + mi * 16 + q * 4 + r;
          int gn = n0 + wn + ni * 16 + r16;
          float v = acc[mi][ni][r];
          if (mode == 1) v *= (float)mask[(long)gm * mask_ld + gn];
          C[coff + (long)gm * ldc + gn] = (bf16)v;
        }
  }
}

// ---------------- final reduce + bias epilogue (FP32 output, (B,S,FD)) -------
__global__ void k_out(const float* __restrict__ Cp, const float* __restrict__ c0,
                      const float* __restrict__ c1, const float* __restrict__ invln,
                      float* __restrict__ out, int nsplit) {
  int i = blockIdx.x * 256 + threadIdx.x;           // 2097152
  int n = i & 2047, m = i >> 11;
  float v = Cp[i];
  if (nsplit == 2) v += Cp[i + 2097152];
  out[i] = v + c0[n] + c1[n] * invln[m];
}

// ---------------- host ----------------

extern "C" void kernel_launch(void* const* d_in, const int* in_sizes, int n_in,
                              void* d_out, int out_size, void* d_ws, size_t ws_size,
                              hipStream_t stream) {
  (void)out_size;
  float* out = (float*)d_out;   // reference output dtype is float32

  // ---- resolve inputs by size (order-agnostic) ----
  int iresid = -1, iln = -1, iprobs = -1, iencb = -1, ipruned = -1, imask = -1;
  int iwo = -1, iwv = -1, iencw = -1, iupdw = -1, ibdec = -1, iupb = -1;
  for (int i = 0; i < n_in; i++) {
    switch (in_sizes[i]) {
      case 786432:  iresid  = i; break;
      case 1024:    iln     = i; break;
      case 3145728: iprobs  = i; break;
      case 2048:    iencb   = i; break;
      case 2097152: ipruned = i; break;
      case 4194304: imask   = i; break;
      case 589824:  if (iwo   < 0) iwo   = i; else iwv   = i; break;
      case 1572864: if (iencw < 0) iencw = i; else iupdw = i; break;
      case 768:     if (ibdec < 0) ibdec = i; else iupb  = i; break;
      default: break;
    }
  }
  bool ok = n_in == 12 && iresid >= 0 && iln >= 0 && iprobs >= 0 && iencb >= 0 &&
            ipruned >= 0 && imask >= 0 && iwo >= 0 && iwv >= 0 && iencw >= 0 &&
            iupdw >= 0 && ibdec >= 0 && iupb >= 0;
  if (!ok) { k_sentinel<<<8192, 256, 0, stream>>>(out); return; }

  const float* resid = (const float*)d_in[iresid];
  const float* lns   = (const float*)d_in[iln];
  const float* probs = (const float*)d_in[iprobs];
  const float* W_O   = (const float*)d_in[iwo];
  const float* W_V   = (const float*)d_in[iwv];
  const float* enc_W = (const float*)d_in[iencw];
  const float* enc_b = (const float*)d_in[iencb];
  const float* b_dec = (const float*)d_in[ibdec];
  const float* updW  = (const float*)d_in[iupdw];
  const float* up_b  = (const float*)d_in[iupb];
  const float* pruned= (const float*)d_in[ipruned];
  const int*   cmask = (const int*)d_in[imask];

  // ---- workspace budget: pick head-group size gs and split count ----
  const size_t fixedB =
      2359296ull + 2359296ull + 3145728ull + 1572864ull + 4194304ull +
      6291456ull + 3145728ull + 6291456ull + 65536ull;
  auto abBytes = [](int g) -> size_t {
    return (size_t)1024 * g * 2816 * 2 + (size_t)2048 * g * 2816 * 2;
  };
  const size_t margin = 4ull << 20;
  int nsplit = 2;
  int gs = 0;
  const int cands[6] = {12, 6, 4, 3, 2, 1};
  for (int ci = 0; ci < 6; ci++) {
    int c = cands[ci];
    if (fixedB + (size_t)nsplit * 1024 * 2048 * 4 + abBytes(c) + margin <= ws_size) { gs = c; break; }
  }
  if (gs == 0) { gs = 1; nsplit = 1; }

  char* p = (char*)d_ws;
  auto alloc = [&](size_t bytes) -> char* {
    char* r = p; p += (bytes + 255) & ~(size_t)255; return r;
  };
  bf16*  WOb    = (bf16*)alloc(12ull * 128 * 768 * 2);
  bf16*  WVb    = (bf16*)alloc(12ull * 768 * 128 * 2);
  bf16*  updWt  = (bf16*)alloc(2048ull * 768 * 2);
  bf16*  Xt     = (bf16*)alloc(4ull * 768 * 256 * 2);
  bf16*  Ut     = (bf16*)alloc(4ull * 2048 * 256 * 2);
  bf16*  E1     = (bf16*)alloc(12ull * 2048 * 128 * 2);
  bf16*  encWb  = (bf16*)alloc(2048ull * 768 * 2);
  bf16*  probsb = (bf16*)alloc(4ull * 12 * 256 * 256 * 2);
  float* invln  = (float*)alloc(1024 * 4);
  float* t_hk   = (float*)alloc(768 * 4);
  float* wv     = (float*)alloc(768 * 4);
  float* c0     = (float*)alloc(2048 * 4);
  float* c1     = (float*)alloc(2048 * 4);
  float* Cpart  = (float*)alloc((size_t)nsplit * 1024 * 2048 * 4);
  bf16*  A_g    = (bf16*)alloc((size_t)1024 * gs * 2816 * 2);
  bf16*  B_g    = (bf16*)alloc((size_t)2048 * gs * 2816 * 2);

  const long Kg = (long)gs * 2816;

  // ---- prep ----
  k_invln<<<4, 256, 0, stream>>>(lns, invln);
  k_cast<<<6144, 256, 0, stream>>>(enc_W, encWb, 1572864);
  k_cast<<<12288, 256, 0, stream>>>(probs, probsb, 3145728);
  k_WO<<<4608, 256, 0, stream>>>(W_O, WOb);
  k_WV<<<4608, 256, 0, stream>>>(W_V, WVb);
  k_updWt<<<6144, 256, 0, stream>>>(updW, updWt);
  k_Xt<<<3072, 256, 0, stream>>>(resid, invln, Xt);
  k_Ut<<<8192, 256, 0, stream>>>(pruned, invln, Ut);
  k_bias_t<<<768, 256, 0, stream>>>(W_V, up_b, t_hk);
  k_bias_w<<<768, 256, 0, stream>>>(W_O, t_hk, wv);
  k_bias_c<<<2048, 256, 0, stream>>>(enc_W, enc_b, b_dec, wv, c0, c1);

  // E1[h][f][k128] = encWb[f,o] . WOb[h][k][o]   M=2048 N=128 K=768 (batched h)
  gemm_bt<<<dim3(1, 16, 12), 256, 0, stream>>>(
      encWb, WOb, E1, 2048, 128, 768,
      768, 768, 128, 12,
      0, 0, 0, (long)128 * 768, 0, (long)2048 * 128,
      0, 0, nullptr, 0);

  // ---- head-group loop ----
  for (int g = 0; g < 12 / gs; g++) {
    // M_g: B_g[f][hh*768 + i] = E1_h[f,k] . WVb_h[i,k]   M=2048 N=768 K=128
    gemm_bt<<<dim3(6, 16, gs), 256, 0, stream>>>(
        E1 + (long)g * gs * 2048 * 128, WVb + (long)g * gs * 768 * 128, B_g,
        2048, 768, 128,
        128, 128, Kg, gs,
        0, (long)2048 * 128, 0, (long)768 * 128, 0, 768,
        0, 0, nullptr, 0);

    // V_g: B_g[f][gs*768 + hh*2048 + u] = mask[f,u] * (M_gh[f,i] . updWt[u,i])  K=768
    gemm_bt<<<dim3(16, 16, gs), 256, 0, stream>>>(
        B_g, updWt, B_g + (long)gs * 768,
        2048, 2048, 768,
        Kg, 768, Kg, gs,
        0, 768, 0, 0, 0, 2048,
        1, 0, cmask, 2048);

    // PX_g: A_g[bq][hh*768 + i] = probsb[b,g*gs+hh][q,s] . Xt[b][i,s]  K=256
    gemm_bt<<<dim3(6, 2, 4 * gs), 256, 0, stream>>>(
        probsb + (long)g * gs * 65536, Xt, A_g,
        256, 768, 256,
        256, 256, Kg, gs,
        (long)12 * 65536, 65536, (long)768 * 256, 0, 256 * Kg, 768,
        0, 0, nullptr, 0);

    // PU_g: A_g[bq][gs*768 + hh*2048 + u] = probsb . Ut[b][u,s]  K=256
    gemm_bt<<<dim3(16, 2, 4 * gs), 256, 0, stream>>>(
        probsb + (long)g * gs * 65536, Ut, A_g + (long)gs * 768,
        256, 2048, 256,
        256, 256, Kg, gs,
        (long)12 * 65536, 65536, (long)2048 * 256, 0, 256 * Kg, 2048,
        0, 0, nullptr, 0);

    // Cpart (+)= A_g[bq,k] . B_g[f,k]   M=1024 N=2048 K=Kg, split-K nsplit
    gemm_bt<<<dim3(16, 8, nsplit), 256, 0, stream>>>(
        A_g, B_g, Cpart,
        1024, 2048, (int)Kg,
        Kg, Kg, 2048, 1,
        0, 0, 0, 0, 0, 0,
        (g == 0) ? 2 : 3, (int)(Kg / nsplit), nullptr, 0);
  }

  // out[b,q,f] = fp32( sum_z Cpart + c0[f] + c1[f]*invln[bq] )
  k_out<<<8192, 256, 0, stream>>>(Cpart, c0, c1, invln, out, nsplit);
}

// Round 16
// 734.238 us; speedup vs baseline: 1.1466x; 1.1466x over previous
//
#include <hip/hip_runtime.h>
#include <hip/hip_bf16.h>
#include <stdint.h>

typedef __bf16 bf16;
typedef __bf16 bf16x8 __attribute__((ext_vector_type(8)));
typedef float f32x4 __attribute__((ext_vector_type(4)));

#define AS1 __attribute__((address_space(1)))
#define AS3 __attribute__((address_space(3)))

// B=4, S=256, H=12, DH=64(pad 128), D=768, FD=2048, FU=2048
// Inputs fp32 + int32 mask. OUTPUT fp32 (R15 green anchor).
// R16: occupancy fix for the final split-K GEMM — (gs,nsplit) preference now
// targets >=1024 blocks on the K=33792 GEMM (R15: 256 blocks, Occupancy 11%,
// MfmaUtil 13%, 440us of 842us total).

__device__ __forceinline__ void gld16(const bf16* g, bf16* l) {
  __builtin_amdgcn_global_load_lds((AS1 void*)g, (AS3 void*)l, 16, 0, 0);
}

__global__ void k_sentinel(float* __restrict__ out) {
  int i = blockIdx.x * 256 + threadIdx.x;
  if (i < 2097152) out[i] = 1048576.0f;
}

// ---------------- prep kernels ----------------

__global__ void k_invln(const float* __restrict__ ln, float* __restrict__ invln) {
  int i = blockIdx.x * 256 + threadIdx.x;
  if (i < 1024) invln[i] = 1.0f / ln[i];
}

__global__ void k_cast(const float* __restrict__ s, bf16* __restrict__ d, int n) {
  int i = blockIdx.x * 256 + threadIdx.x;
  if (i < n) d[i] = (bf16)s[i];
}

__global__ void k_WO(const float* __restrict__ W_O, bf16* __restrict__ WOb) {
  int i = blockIdx.x * 256 + threadIdx.x;           // 12*128*768
  int o = i % 768, r = (i / 768) & 127, h = i / (768 * 128);
  WOb[i] = (r < 64) ? (bf16)W_O[(long)(h * 64 + r) * 768 + o] : (bf16)0.0f;
}

__global__ void k_WV(const float* __restrict__ W_V, bf16* __restrict__ WVb) {
  int i = blockIdx.x * 256 + threadIdx.x;           // 12*768*128
  int k = i & 127, m = (i / 128) % 768, h = i / (128 * 768);
  WVb[i] = (k < 64) ? (bf16)W_V[(long)(h * 768 + m) * 64 + k] : (bf16)0.0f;
}

__global__ void k_updWt(const float* __restrict__ u, bf16* __restrict__ d) {
  int i = blockIdx.x * 256 + threadIdx.x;           // 2048*768
  int ii = i % 768, uu = i / 768;
  d[i] = (bf16)u[(long)ii * 2048 + uu];
}

__global__ void k_Xt(const float* __restrict__ resid, const float* __restrict__ invln,
                     bf16* __restrict__ Xt) {
  int i = blockIdx.x * 256 + threadIdx.x;           // 4*768*256
  int s = i & 255, d = (i >> 8) % 768, b = i / (768 * 256);
  int bs = b * 256 + s;
  Xt[i] = (bf16)(resid[(long)bs * 768 + d] * invln[bs]);
}

__global__ void k_Ut(const float* __restrict__ pr, const float* __restrict__ invln,
                     bf16* __restrict__ Ut) {
  int i = blockIdx.x * 256 + threadIdx.x;           // 4*2048*256
  int s = i & 255, u = (i >> 8) & 2047, b = i / (2048 * 256);
  int bs = b * 256 + s;
  Ut[i] = (bf16)(pr[(long)bs * 2048 + u] * invln[bs]);
}

// ---------------- bias chain (fp32, block-parallel) ----------------

__device__ __forceinline__ float blk_reduce(float s) {
  __shared__ float red[256];
  red[threadIdx.x] = s; __syncthreads();
  for (int o = 128; o > 0; o >>= 1) {
    if ((int)threadIdx.x < o) red[threadIdx.x] += red[threadIdx.x + o];
    __syncthreads();
  }
  float r = red[0]; __syncthreads();
  return r;
}

__global__ void k_bias_t(const float* __restrict__ W_V, const float* __restrict__ up_b,
                         float* __restrict__ t_hk) {
  int j = blockIdx.x, h = j >> 6, k = j & 63;
  float s = 0.f;
  for (int m = threadIdx.x; m < 768; m += 256)
    s += W_V[((long)(h * 768 + m)) * 64 + k] * up_b[m];
  float r = blk_reduce(s);
  if (threadIdx.x == 0) t_hk[j] = r;
}

__global__ void k_bias_w(const float* __restrict__ W_O, const float* __restrict__ t_hk,
                         float* __restrict__ w) {
  int d = blockIdx.x;
  float s = 0.f;
  for (int j = threadIdx.x; j < 768; j += 256)
    s += W_O[(long)j * 768 + d] * t_hk[j];
  float r = blk_reduce(s);
  if (threadIdx.x == 0) w[d] = r;
}

__global__ void k_bias_c(const float* __restrict__ enc_W, const float* __restrict__ enc_b,
                         const float* __restrict__ b_dec, const float* __restrict__ w,
                         float* __restrict__ c0, float* __restrict__ c1) {
  int f = blockIdx.x;
  float s0 = 0.f, s1 = 0.f;
  for (int d = threadIdx.x; d < 768; d += 256) {
    float e = enc_W[(long)f * 768 + d];
    s0 += e * b_dec[d];
    s1 += e * w[d];
  }
  float r0 = blk_reduce(s0);
  float r1 = blk_reduce(s1);
  if (threadIdx.x == 0) { c0[f] = enc_b[f] - r0; c1[f] = r1; }
}

// ---------------- GEMM (BT form: C[m,n] = sum_k A[m,k]*B[n,k]) ----------------
// mode 0: bf16 store; mode 1: *= mask, bf16 store;
// mode 2: split-K fp32 overwrite; mode 3: split-K fp32 read-accumulate
__global__ __launch_bounds__(256)
void gemm_bt(const bf16* __restrict__ A, const bf16* __restrict__ B, void* __restrict__ Cv,
             int M, int N, int K,
             long lda, long ldb, long ldc,
             int batchH,
             long sa_b, long sa_h, long sb_b, long sb_h, long sc_b, long sc_h,
             int mode, int kChunk,
             const int* __restrict__ mask, long mask_ld)
{
  __shared__ __align__(16) bf16 Asm[128 * 32];
  __shared__ __align__(16) bf16 Bsm[128 * 32];

  const int t = threadIdx.x;
  const int m0 = blockIdx.y * 128;
  const int n0 = blockIdx.x * 128;

  long aoff, boff, coff;
  int k0, k1;
  if (mode >= 2) {
    int z = blockIdx.z;
    aoff = 0; boff = 0;
    coff = (long)z * (long)M * ldc;
    k0 = z * kChunk; k1 = k0 + kChunk; if (k1 > K) k1 = K;
  } else {
    int z = blockIdx.z;
    int bb = z / batchH, hh = z - bb * batchH;
    aoff = (long)bb * sa_b + (long)hh * sa_h;
    boff = (long)bb * sb_b + (long)hh * sb_h;
    coff = (long)bb * sc_b + (long)hh * sc_h;
    k0 = 0; k1 = K;
  }

  const bf16* Ab = A + aoff + (long)m0 * lda;
  const bf16* Bb = B + boff + (long)n0 * ldb;

  const int r0 = t >> 2;           // 0..63
  const int kk = (t & 3) << 3;     // 0,8,16,24

  const int L = t & 63, w = t >> 6;
  const int wm = (w & 1) * 64, wn = (w >> 1) * 64;
  const int r16 = L & 15, q = L >> 4;

  f32x4 acc[4][4];
#pragma unroll
  for (int i = 0; i < 4; i++)
#pragma unroll
    for (int j = 0; j < 4; j++) acc[i][j] = (f32x4){0.f, 0.f, 0.f, 0.f};

  for (int kt = k0; kt < k1; kt += 32) {
    gld16(Ab + (long)r0 * lda + (kt + kk),        &Asm[t * 8]);
    gld16(Ab + (long)(r0 + 64) * lda + (kt + kk), &Asm[2048 + t * 8]);
    gld16(Bb + (long)r0 * ldb + (kt + kk),        &Bsm[t * 8]);
    gld16(Bb + (long)(r0 + 64) * ldb + (kt + kk), &Bsm[2048 + t * 8]);
    __syncthreads();

    bf16x8 af[4], bfr[4];
#pragma unroll
    for (int i = 0; i < 4; i++) {
      af[i]  = *(const bf16x8*)&Asm[(wm + i * 16 + r16) * 32 + q * 8];
      bfr[i] = *(const bf16x8*)&Bsm[(wn + i * 16 + r16) * 32 + q * 8];
    }
#pragma unroll
    for (int mi = 0; mi < 4; mi++)
#pragma unroll
      for (int ni = 0; ni < 4; ni++)
        acc[mi][ni] = __builtin_amdgcn_mfma_f32_16x16x32_bf16(af[mi], bfr[ni], acc[mi][ni], 0, 0, 0);
    __syncthreads();
  }

  if (mode >= 2) {
    float* C = (float*)Cv;
#pragma unroll
    for (int mi = 0; mi < 4; mi++)
#pragma unroll
      for (int ni = 0; ni < 4; ni++)
#pragma unroll
        for (int r = 0; r < 4; r++) {
          int gm = m0 + wm + mi * 16 + q * 4 + r;
          int gn = n0 + wn + ni * 16 + r16;
          long idx = coff + (long)gm * ldc + gn;
          float v = acc[mi][ni][r];
          if (mode == 3) v += C[idx];
          C[idx] = v;
        }
  } else {
    bf16* C = (bf16*)Cv;
#pragma unroll
    for (int mi = 0; mi < 4; mi++)
#pragma unroll
      for (int ni = 0; ni < 4; ni++)
#pragma unroll
        for (int r = 0; r < 4; r++) {
          int gm = m0 + wm + mi * 16 + q * 4 + r;
          int gn = n0 + wn + ni * 16 + r16;
          float v = acc[mi][ni][r];
          if (mode == 1) v *= (float)mask[(long)gm * mask_ld + gn];
          C[coff + (long)gm * ldc + gn] = (bf16)v;
        }
  }
}

// ---------------- final reduce + bias epilogue (fp32 out, (B,S,FD)) ----------
__global__ void k_out(const float* __restrict__ Cp, const float* __restrict__ c0,
                      const float* __restrict__ c1, const float* __restrict__ invln,
                      float* __restrict__ out, int nsplit) {
  int i = blockIdx.x * 256 + threadIdx.x;           // 2097152
  int n = i & 2047, m = i >> 11;
  float v = Cp[i];
  for (int z = 1; z < nsplit; z++) v += Cp[i + (long)z * 2097152];
  out[i] = v + c0[n] + c1[n] * invln[m];
}

// ---------------- host ----------------

extern "C" void kernel_launch(void* const* d_in, const int* in_sizes, int n_in,
                              void* d_out, int out_size, void* d_ws, size_t ws_size,
                              hipStream_t stream) {
  (void)out_size;
  float* out = (float*)d_out;

  // ---- resolve inputs by size (order-agnostic) ----
  int iresid = -1, iln = -1, iprobs = -1, iencb = -1, ipruned = -1, imask = -1;
  int iwo = -1, iwv = -1, iencw = -1, iupdw = -1, ibdec = -1, iupb = -1;
  for (int i = 0; i < n_in; i++) {
    switch (in_sizes[i]) {
      case 786432:  iresid  = i; break;
      case 1024:    iln     = i; break;
      case 3145728: iprobs  = i; break;
      case 2048:    iencb   = i; break;
      case 2097152: ipruned = i; break;
      case 4194304: imask   = i; break;
      case 589824:  if (iwo   < 0) iwo   = i; else iwv   = i; break;
      case 1572864: if (iencw < 0) iencw = i; else iupdw = i; break;
      case 768:     if (ibdec < 0) ibdec = i; else iupb  = i; break;
      default: break;
    }
  }
  bool ok = n_in == 12 && iresid >= 0 && iln >= 0 && iprobs >= 0 && iencb >= 0 &&
            ipruned >= 0 && imask >= 0 && iwo >= 0 && iwv >= 0 && iencw >= 0 &&
            iupdw >= 0 && ibdec >= 0 && iupb >= 0;
  if (!ok) { k_sentinel<<<8192, 256, 0, stream>>>(out); return; }

  const float* resid = (const float*)d_in[iresid];
  const float* lns   = (const float*)d_in[iln];
  const float* probs = (const float*)d_in[iprobs];
  const float* W_O   = (const float*)d_in[iwo];
  const float* W_V   = (const float*)d_in[iwv];
  const float* enc_W = (const float*)d_in[iencw];
  const float* enc_b = (const float*)d_in[iencb];
  const float* b_dec = (const float*)d_in[ibdec];
  const float* updW  = (const float*)d_in[iupdw];
  const float* up_b  = (const float*)d_in[iupb];
  const float* pruned= (const float*)d_in[ipruned];
  const int*   cmask = (const int*)d_in[imask];

  // ---- workspace config: prefer deep split-K for final-GEMM occupancy ----
  // final GEMM grid = 16 x 8 x nsplit blocks; want >= 1024 (4 blocks/CU).
  const size_t fixedB =
      2359296ull + 2359296ull + 3145728ull + 1572864ull + 4194304ull +
      6291456ull + 3145728ull + 6291456ull + 65536ull;
  auto abBytes = [](int g) -> size_t {
    return (size_t)1024 * g * 2816 * 2 + (size_t)2048 * g * 2816 * 2;
  };
  const size_t margin = 4ull << 20;
  const int cgs[9] = {12, 6, 6, 4, 3, 2, 2, 1, 1};
  const int cns[9] = { 8, 8, 4, 4, 4, 4, 2, 2, 1};
  int gs = 0, nsplit = 0;
  for (int ci = 0; ci < 9; ci++) {
    if (fixedB + (size_t)cns[ci] * 1024 * 2048 * 4 + abBytes(cgs[ci]) + margin <= ws_size) {
      gs = cgs[ci]; nsplit = cns[ci]; break;
    }
  }
  if (gs == 0) { gs = 1; nsplit = 1; }

  char* p = (char*)d_ws;
  auto alloc = [&](size_t bytes) -> char* {
    char* r = p; p += (bytes + 255) & ~(size_t)255; return r;
  };
  bf16*  WOb    = (bf16*)alloc(12ull * 128 * 768 * 2);
  bf16*  WVb    = (bf16*)alloc(12ull * 768 * 128 * 2);
  bf16*  updWt  = (bf16*)alloc(2048ull * 768 * 2);
  bf16*  Xt     = (bf16*)alloc(4ull * 768 * 256 * 2);
  bf16*  Ut     = (bf16*)alloc(4ull * 2048 * 256 * 2);
  bf16*  E1     = (bf16*)alloc(12ull * 2048 * 128 * 2);
  bf16*  encWb  = (bf16*)alloc(2048ull * 768 * 2);
  bf16*  probsb = (bf16*)alloc(4ull * 12 * 256 * 256 * 2);
  float* invln  = (float*)alloc(1024 * 4);
  float* t_hk   = (float*)alloc(768 * 4);
  float* wv     = (float*)alloc(768 * 4);
  float* c0     = (float*)alloc(2048 * 4);
  float* c1     = (float*)alloc(2048 * 4);
  float* Cpart  = (float*)alloc((size_t)nsplit * 1024 * 2048 * 4);
  bf16*  A_g    = (bf16*)alloc((size_t)1024 * gs * 2816 * 2);
  bf16*  B_g    = (bf16*)alloc((size_t)2048 * gs * 2816 * 2);

  const long Kg = (long)gs * 2816;

  // ---- prep ----
  k_invln<<<4, 256, 0, stream>>>(lns, invln);
  k_cast<<<6144, 256, 0, stream>>>(enc_W, encWb, 1572864);
  k_cast<<<12288, 256, 0, stream>>>(probs, probsb, 3145728);
  k_WO<<<4608, 256, 0, stream>>>(W_O, WOb);
  k_WV<<<4608, 256, 0, stream>>>(W_V, WVb);
  k_updWt<<<6144, 256, 0, stream>>>(updW, updWt);
  k_Xt<<<3072, 256, 0, stream>>>(resid, invln, Xt);
  k_Ut<<<8192, 256, 0, stream>>>(pruned, invln, Ut);
  k_bias_t<<<768, 256, 0, stream>>>(W_V, up_b, t_hk);
  k_bias_w<<<768, 256, 0, stream>>>(W_O, t_hk, wv);
  k_bias_c<<<2048, 256, 0, stream>>>(enc_W, enc_b, b_dec, wv, c0, c1);

  // E1[h][f][k128] = encWb[f,o] . WOb[h][k][o]   M=2048 N=128 K=768 (batched h)
  gemm_bt<<<dim3(1, 16, 12), 256, 0, stream>>>(
      encWb, WOb, E1, 2048, 128, 768,
      768, 768, 128, 12,
      0, 0, 0, (long)128 * 768, 0, (long)2048 * 128,
      0, 0, nullptr, 0);

  // ---- head-group loop ----
  for (int g = 0; g < 12 / gs; g++) {
    // M_g: B_g[f][hh*768 + i] = E1_h[f,k] . WVb_h[i,k]   M=2048 N=768 K=128
    gemm_bt<<<dim3(6, 16, gs), 256, 0, stream>>>(
        E1 + (long)g * gs * 2048 * 128, WVb + (long)g * gs * 768 * 128, B_g,
        2048, 768, 128,
        128, 128, Kg, gs,
        0, (long)2048 * 128, 0, (long)768 * 128, 0, 768,
        0, 0, nullptr, 0);

    // V_g: B_g[f][gs*768 + hh*2048 + u] = mask[f,u] * (M_gh[f,i] . updWt[u,i])  K=768
    gemm_bt<<<dim3(16, 16, gs), 256, 0, stream>>>(
        B_g, updWt, B_g + (long)gs * 768,
        2048, 2048, 768,
        Kg, 768, Kg, gs,
        0, 768, 0, 0, 0, 2048,
        1, 0, cmask, 2048);

    // PX_g: A_g[bq][hh*768 + i] = probsb[b,g*gs+hh][q,s] . Xt[b][i,s]  K=256
    gemm_bt<<<dim3(6, 2, 4 * gs), 256, 0, stream>>>(
        probsb + (long)g * gs * 65536, Xt, A_g,
        256, 768, 256,
        256, 256, Kg, gs,
        (long)12 * 65536, 65536, (long)768 * 256, 0, 256 * Kg, 768,
        0, 0, nullptr, 0);

    // PU_g: A_g[bq][gs*768 + hh*2048 + u] = probsb . Ut[b][u,s]  K=256
    gemm_bt<<<dim3(16, 2, 4 * gs), 256, 0, stream>>>(
        probsb + (long)g * gs * 65536, Ut, A_g + (long)gs * 768,
        256, 2048, 256,
        256, 256, Kg, gs,
        (long)12 * 65536, 65536, (long)2048 * 256, 0, 256 * Kg, 2048,
        0, 0, nullptr, 0);

    // Cpart (+)= A_g[bq,k] . B_g[f,k]   M=1024 N=2048 K=Kg, split-K nsplit
    gemm_bt<<<dim3(16, 8, nsplit), 256, 0, stream>>>(
        A_g, B_g, Cpart,
        1024, 2048, (int)Kg,
        Kg, Kg, 2048, 1,
        0, 0, 0, 0, 0, 0,
        (g == 0) ? 2 : 3, (int)(Kg / nsplit), nullptr, 0);
  }

  // out[b,q,f] = fp32( sum_z Cpart + c0[f] + c1[f]*invln[bq] )
  k_out<<<8192, 256, 0, stream>>>(Cpart, c0, c1, invln, out, nsplit);
}

// Round 17
// 689.863 us; speedup vs baseline: 1.2204x; 1.0643x over previous
//
#include <hip/hip_runtime.h>
#include <hip/hip_bf16.h>
#include <stdint.h>

typedef __bf16 bf16;
typedef __bf16 bf16x8 __attribute__((ext_vector_type(8)));
typedef float f32x4 __attribute__((ext_vector_type(4)));

#define AS1 __attribute__((address_space(1)))
#define AS3 __attribute__((address_space(3)))

// B=4, S=256, H=12, DH=64(pad 128), D=768, FD=2048, FU=2048
// Inputs fp32 + int32 mask. OUTPUT fp32.
// R17: BK=64 staging with XOR source-swizzle (bank-conflict-free frag reads
// under global_load_lds's fixed dst constraint) + float4 epilogue.

__device__ __forceinline__ void gld16(const bf16* g, bf16* l) {
  __builtin_amdgcn_global_load_lds((AS1 void*)g, (AS3 void*)l, 16, 0, 0);
}

__global__ void k_sentinel(float* __restrict__ out) {
  int i = blockIdx.x * 256 + threadIdx.x;
  if (i < 2097152) out[i] = 1048576.0f;
}

// ---------------- prep kernels ----------------

__global__ void k_invln(const float* __restrict__ ln, float* __restrict__ invln) {
  int i = blockIdx.x * 256 + threadIdx.x;
  if (i < 1024) invln[i] = 1.0f / ln[i];
}

__global__ void k_cast(const float* __restrict__ s, bf16* __restrict__ d, int n) {
  int i = blockIdx.x * 256 + threadIdx.x;
  if (i < n) d[i] = (bf16)s[i];
}

__global__ void k_WO(const float* __restrict__ W_O, bf16* __restrict__ WOb) {
  int i = blockIdx.x * 256 + threadIdx.x;           // 12*128*768
  int o = i % 768, r = (i / 768) & 127, h = i / (768 * 128);
  WOb[i] = (r < 64) ? (bf16)W_O[(long)(h * 64 + r) * 768 + o] : (bf16)0.0f;
}

__global__ void k_WV(const float* __restrict__ W_V, bf16* __restrict__ WVb) {
  int i = blockIdx.x * 256 + threadIdx.x;           // 12*768*128
  int k = i & 127, m = (i / 128) % 768, h = i / (128 * 768);
  WVb[i] = (k < 64) ? (bf16)W_V[(long)(h * 768 + m) * 64 + k] : (bf16)0.0f;
}

__global__ void k_updWt(const float* __restrict__ u, bf16* __restrict__ d) {
  int i = blockIdx.x * 256 + threadIdx.x;           // 2048*768
  int ii = i % 768, uu = i / 768;
  d[i] = (bf16)u[(long)ii * 2048 + uu];
}

__global__ void k_Xt(const float* __restrict__ resid, const float* __restrict__ invln,
                     bf16* __restrict__ Xt) {
  int i = blockIdx.x * 256 + threadIdx.x;           // 4*768*256
  int s = i & 255, d = (i >> 8) % 768, b = i / (768 * 256);
  int bs = b * 256 + s;
  Xt[i] = (bf16)(resid[(long)bs * 768 + d] * invln[bs]);
}

__global__ void k_Ut(const float* __restrict__ pr, const float* __restrict__ invln,
                     bf16* __restrict__ Ut) {
  int i = blockIdx.x * 256 + threadIdx.x;           // 4*2048*256
  int s = i & 255, u = (i >> 8) & 2047, b = i / (2048 * 256);
  int bs = b * 256 + s;
  Ut[i] = (bf16)(pr[(long)bs * 2048 + u] * invln[bs]);
}

// ---------------- bias chain (fp32, block-parallel) ----------------

__device__ __forceinline__ float blk_reduce(float s) {
  __shared__ float red[256];
  red[threadIdx.x] = s; __syncthreads();
  for (int o = 128; o > 0; o >>= 1) {
    if ((int)threadIdx.x < o) red[threadIdx.x] += red[threadIdx.x + o];
    __syncthreads();
  }
  float r = red[0]; __syncthreads();
  return r;
}

__global__ void k_bias_t(const float* __restrict__ W_V, const float* __restrict__ up_b,
                         float* __restrict__ t_hk) {
  int j = blockIdx.x, h = j >> 6, k = j & 63;
  float s = 0.f;
  for (int m = threadIdx.x; m < 768; m += 256)
    s += W_V[((long)(h * 768 + m)) * 64 + k] * up_b[m];
  float r = blk_reduce(s);
  if (threadIdx.x == 0) t_hk[j] = r;
}

__global__ void k_bias_w(const float* __restrict__ W_O, const float* __restrict__ t_hk,
                         float* __restrict__ w) {
  int d = blockIdx.x;
  float s = 0.f;
  for (int j = threadIdx.x; j < 768; j += 256)
    s += W_O[(long)j * 768 + d] * t_hk[j];
  float r = blk_reduce(s);
  if (threadIdx.x == 0) w[d] = r;
}

__global__ void k_bias_c(const float* __restrict__ enc_W, const float* __restrict__ enc_b,
                         const float* __restrict__ b_dec, const float* __restrict__ w,
                         float* __restrict__ c0, float* __restrict__ c1) {
  int f = blockIdx.x;
  float s0 = 0.f, s1 = 0.f;
  for (int d = threadIdx.x; d < 768; d += 256) {
    float e = enc_W[(long)f * 768 + d];
    s0 += e * b_dec[d];
    s1 += e * w[d];
  }
  float r0 = blk_reduce(s0);
  float r1 = blk_reduce(s1);
  if (threadIdx.x == 0) { c0[f] = enc_b[f] - r0; c1[f] = r1; }
}

// ---------------- GEMM (BT form: C[m,n] = sum_k A[m,k]*B[n,k]) ----------------
// BK=64, XOR-swizzled staging. K (and kChunk) must be multiples of 64.
// mode 0: bf16 store; mode 1: *= mask, bf16 store;
// mode 2: split-K fp32 overwrite; mode 3: split-K fp32 read-accumulate
__global__ __launch_bounds__(256)
void gemm_bt(const bf16* __restrict__ A, const bf16* __restrict__ B, void* __restrict__ Cv,
             int M, int N, int K,
             long lda, long ldb, long ldc,
             int batchH,
             long sa_b, long sa_h, long sb_b, long sb_h, long sc_b, long sc_h,
             int mode, int kChunk,
             const int* __restrict__ mask, long mask_ld)
{
  __shared__ __align__(16) bf16 Asm[128 * 64];
  __shared__ __align__(16) bf16 Bsm[128 * 64];

  const int t = threadIdx.x;
  const int m0 = blockIdx.y * 128;
  const int n0 = blockIdx.x * 128;

  long aoff, boff, coff;
  int k0, k1;
  if (mode >= 2) {
    int z = blockIdx.z;
    aoff = 0; boff = 0;
    coff = (long)z * (long)M * ldc;
    k0 = z * kChunk; k1 = k0 + kChunk; if (k1 > K) k1 = K;
  } else {
    int z = blockIdx.z;
    int bb = z / batchH, hh = z - bb * batchH;
    aoff = (long)bb * sa_b + (long)hh * sa_h;
    boff = (long)bb * sb_b + (long)hh * sb_h;
    coff = (long)bb * sc_b + (long)hh * sc_h;
    k0 = 0; k1 = K;
  }

  const bf16* Ab = A + aoff + (long)m0 * lda;
  const bf16* Bb = B + boff + (long)n0 * ldb;

  const int r0 = t >> 3;           // 0..31 (staging row within 32-row group)
  const int g8 = t & 7;            // staging col-group (LDS slot)

  const int L = t & 63, w = t >> 6;
  const int wm = (w & 1) * 64, wn = (w >> 1) * 64;
  const int r16 = L & 15, q = L >> 4;

  f32x4 acc[4][4];
#pragma unroll
  for (int i = 0; i < 4; i++)
#pragma unroll
    for (int j = 0; j < 4; j++) acc[i][j] = (f32x4){0.f, 0.f, 0.f, 0.f};

  for (int kt = k0; kt < k1; kt += 64) {
#pragma unroll
    for (int j = 0; j < 4; j++) {
      int row = j * 32 + r0;
      int sc = ((g8 ^ (row & 7)) << 3);      // source col swizzle
      gld16(Ab + (long)row * lda + (kt + sc), &Asm[j * 2048 + t * 8]);
      gld16(Bb + (long)row * ldb + (kt + sc), &Bsm[j * 2048 + t * 8]);
    }
    __syncthreads();

#pragma unroll
    for (int h2 = 0; h2 < 2; h2++) {
      bf16x8 af[4], bfr[4];
#pragma unroll
      for (int i = 0; i < 4; i++) {
        int ra = wm + i * 16 + r16;
        af[i]  = *(const bf16x8*)&Asm[ra * 64 + ((((h2 << 2) + q) ^ (ra & 7)) << 3)];
        int rb = wn + i * 16 + r16;
        bfr[i] = *(const bf16x8*)&Bsm[rb * 64 + ((((h2 << 2) + q) ^ (rb & 7)) << 3)];
      }
#pragma unroll
      for (int mi = 0; mi < 4; mi++)
#pragma unroll
        for (int ni = 0; ni < 4; ni++)
          acc[mi][ni] = __builtin_amdgcn_mfma_f32_16x16x32_bf16(af[mi], bfr[ni], acc[mi][ni], 0, 0, 0);
    }
    __syncthreads();
  }

  if (mode >= 2) {
    float* C = (float*)Cv;
#pragma unroll
    for (int mi = 0; mi < 4; mi++)
#pragma unroll
      for (int ni = 0; ni < 4; ni++)
#pragma unroll
        for (int r = 0; r < 4; r++) {
          int gm = m0 + wm + mi * 16 + q * 4 + r;
          int gn = n0 + wn + ni * 16 + r16;
          long idx = coff + (long)gm * ldc + gn;
          float v = acc[mi][ni][r];
          if (mode == 3) v += C[idx];
          C[idx] = v;
        }
  } else {
    bf16* C = (bf16*)Cv;
#pragma unroll
    for (int mi = 0; mi < 4; mi++)
#pragma unroll
      for (int ni = 0; ni < 4; ni++)
#pragma unroll
        for (int r = 0; r < 4; r++) {
          int gm = m0 + wm + mi * 16 + q * 4 + r;
          int gn = n0 + wn + ni * 16 + r16;
          float v = acc[mi][ni][r];
          if (mode == 1) v *= (float)mask[(long)gm * mask_ld + gn];
          C[coff + (long)gm * ldc + gn] = (bf16)v;
        }
  }
}

// ---------------- final reduce + bias epilogue (fp32 out, float4) ------------
__global__ void k_out(const float* __restrict__ Cp, const float* __restrict__ c0,
                      const float* __restrict__ c1, const float* __restrict__ invln,
                      float* __restrict__ out, int nsplit) {
  int i4 = blockIdx.x * 256 + threadIdx.x;          // 524288
  long i = (long)i4 * 4;
  int n = (int)(i & 2047), m = (int)(i >> 11);
  float4 v = *(const float4*)(Cp + i);
  for (int z = 1; z < nsplit; z++) {
    float4 u = *(const float4*)(Cp + i + (long)z * 2097152);
    v.x += u.x; v.y += u.y; v.z += u.z; v.w += u.w;
  }
  float il = invln[m];
  float4 a = *(const float4*)(c0 + n);
  float4 b = *(const float4*)(c1 + n);
  v.x += a.x + b.x * il;
  v.y += a.y + b.y * il;
  v.z += a.z + b.z * il;
  v.w += a.w + b.w * il;
  *(float4*)(out + i) = v;
}

// ---------------- host ----------------

extern "C" void kernel_launch(void* const* d_in, const int* in_sizes, int n_in,
                              void* d_out, int out_size, void* d_ws, size_t ws_size,
                              hipStream_t stream) {
  (void)out_size;
  float* out = (float*)d_out;

  // ---- resolve inputs by size (order-agnostic) ----
  int iresid = -1, iln = -1, iprobs = -1, iencb = -1, ipruned = -1, imask = -1;
  int iwo = -1, iwv = -1, iencw = -1, iupdw = -1, ibdec = -1, iupb = -1;
  for (int i = 0; i < n_in; i++) {
    switch (in_sizes[i]) {
      case 786432:  iresid  = i; break;
      case 1024:    iln     = i; break;
      case 3145728: iprobs  = i; break;
      case 2048:    iencb   = i; break;
      case 2097152: ipruned = i; break;
      case 4194304: imask   = i; break;
      case 589824:  if (iwo   < 0) iwo   = i; else iwv   = i; break;
      case 1572864: if (iencw < 0) iencw = i; else iupdw = i; break;
      case 768:     if (ibdec < 0) ibdec = i; else iupb  = i; break;
      default: break;
    }
  }
  bool ok = n_in == 12 && iresid >= 0 && iln >= 0 && iprobs >= 0 && iencb >= 0 &&
            ipruned >= 0 && imask >= 0 && iwo >= 0 && iwv >= 0 && iencw >= 0 &&
            iupdw >= 0 && ibdec >= 0 && iupb >= 0;
  if (!ok) { k_sentinel<<<8192, 256, 0, stream>>>(out); return; }

  const float* resid = (const float*)d_in[iresid];
  const float* lns   = (const float*)d_in[iln];
  const float* probs = (const float*)d_in[iprobs];
  const float* W_O   = (const float*)d_in[iwo];
  const float* W_V   = (const float*)d_in[iwv];
  const float* enc_W = (const float*)d_in[iencw];
  const float* enc_b = (const float*)d_in[iencb];
  const float* b_dec = (const float*)d_in[ibdec];
  const float* updW  = (const float*)d_in[iupdw];
  const float* up_b  = (const float*)d_in[iupb];
  const float* pruned= (const float*)d_in[ipruned];
  const int*   cmask = (const int*)d_in[imask];

  // ---- workspace config: deep split-K for final-GEMM occupancy ----
  const size_t fixedB =
      2359296ull + 2359296ull + 3145728ull + 1572864ull + 4194304ull +
      6291456ull + 3145728ull + 6291456ull + 65536ull;
  auto abBytes = [](int g) -> size_t {
    return (size_t)1024 * g * 2816 * 2 + (size_t)2048 * g * 2816 * 2;
  };
  const size_t margin = 4ull << 20;
  const int cgs[9] = {12, 6, 6, 4, 3, 2, 2, 1, 1};
  const int cns[9] = { 8, 8, 4, 4, 4, 4, 2, 2, 1};
  int gs = 0, nsplit = 0;
  for (int ci = 0; ci < 9; ci++) {
    if (fixedB + (size_t)cns[ci] * 1024 * 2048 * 4 + abBytes(cgs[ci]) + margin <= ws_size) {
      gs = cgs[ci]; nsplit = cns[ci]; break;
    }
  }
  if (gs == 0) { gs = 1; nsplit = 1; }

  char* p = (char*)d_ws;
  auto alloc = [&](size_t bytes) -> char* {
    char* r = p; p += (bytes + 255) & ~(size_t)255; return r;
  };
  bf16*  WOb    = (bf16*)alloc(12ull * 128 * 768 * 2);
  bf16*  WVb    = (bf16*)alloc(12ull * 768 * 128 * 2);
  bf16*  updWt  = (bf16*)alloc(2048ull * 768 * 2);
  bf16*  Xt     = (bf16*)alloc(4ull * 768 * 256 * 2);
  bf16*  Ut     = (bf16*)alloc(4ull * 2048 * 256 * 2);
  bf16*  E1     = (bf16*)alloc(12ull * 2048 * 128 * 2);
  bf16*  encWb  = (bf16*)alloc(2048ull * 768 * 2);
  bf16*  probsb = (bf16*)alloc(4ull * 12 * 256 * 256 * 2);
  float* invln  = (float*)alloc(1024 * 4);
  float* t_hk   = (float*)alloc(768 * 4);
  float* wv     = (float*)alloc(768 * 4);
  float* c0     = (float*)alloc(2048 * 4);
  float* c1     = (float*)alloc(2048 * 4);
  float* Cpart  = (float*)alloc((size_t)nsplit * 1024 * 2048 * 4);
  bf16*  A_g    = (bf16*)alloc((size_t)1024 * gs * 2816 * 2);
  bf16*  B_g    = (bf16*)alloc((size_t)2048 * gs * 2816 * 2);

  const long Kg = (long)gs * 2816;

  // ---- prep ----
  k_invln<<<4, 256, 0, stream>>>(lns, invln);
  k_cast<<<6144, 256, 0, stream>>>(enc_W, encWb, 1572864);
  k_cast<<<12288, 256, 0, stream>>>(probs, probsb, 3145728);
  k_WO<<<4608, 256, 0, stream>>>(W_O, WOb);
  k_WV<<<4608, 256, 0, stream>>>(W_V, WVb);
  k_updWt<<<6144, 256, 0, stream>>>(updW, updWt);
  k_Xt<<<3072, 256, 0, stream>>>(resid, invln, Xt);
  k_Ut<<<8192, 256, 0, stream>>>(pruned, invln, Ut);
  k_bias_t<<<768, 256, 0, stream>>>(W_V, up_b, t_hk);
  k_bias_w<<<768, 256, 0, stream>>>(W_O, t_hk, wv);
  k_bias_c<<<2048, 256, 0, stream>>>(enc_W, enc_b, b_dec, wv, c0, c1);

  // E1[h][f][k128] = encWb[f,o] . WOb[h][k][o]   M=2048 N=128 K=768 (batched h)
  gemm_bt<<<dim3(1, 16, 12), 256, 0, stream>>>(
      encWb, WOb, E1, 2048, 128, 768,
      768, 768, 128, 12,
      0, 0, 0, (long)128 * 768, 0, (long)2048 * 128,
      0, 0, nullptr, 0);

  // ---- head-group loop ----
  for (int g = 0; g < 12 / gs; g++) {
    // M_g: B_g[f][hh*768 + i] = E1_h[f,k] . WVb_h[i,k]   M=2048 N=768 K=128
    gemm_bt<<<dim3(6, 16, gs), 256, 0, stream>>>(
        E1 + (long)g * gs * 2048 * 128, WVb + (long)g * gs * 768 * 128, B_g,
        2048, 768, 128,
        128, 128, Kg, gs,
        0, (long)2048 * 128, 0, (long)768 * 128, 0, 768,
        0, 0, nullptr, 0);

    // V_g: B_g[f][gs*768 + hh*2048 + u] = mask[f,u] * (M_gh[f,i] . updWt[u,i])  K=768
    gemm_bt<<<dim3(16, 16, gs), 256, 0, stream>>>(
        B_g, updWt, B_g + (long)gs * 768,
        2048, 2048, 768,
        Kg, 768, Kg, gs,
        0, 768, 0, 0, 0, 2048,
        1, 0, cmask, 2048);

    // PX_g: A_g[bq][hh*768 + i] = probsb[b,g*gs+hh][q,s] . Xt[b][i,s]  K=256
    gemm_bt<<<dim3(6, 2, 4 * gs), 256, 0, stream>>>(
        probsb + (long)g * gs * 65536, Xt, A_g,
        256, 768, 256,
        256, 256, Kg, gs,
        (long)12 * 65536, 65536, (long)768 * 256, 0, 256 * Kg, 768,
        0, 0, nullptr, 0);

    // PU_g: A_g[bq][gs*768 + hh*2048 + u] = probsb . Ut[b][u,s]  K=256
    gemm_bt<<<dim3(16, 2, 4 * gs), 256, 0, stream>>>(
        probsb + (long)g * gs * 65536, Ut, A_g + (long)gs * 768,
        256, 2048, 256,
        256, 256, Kg, gs,
        (long)12 * 65536, 65536, (long)2048 * 256, 0, 256 * Kg, 2048,
        0, 0, nullptr, 0);

    // Cpart (+)= A_g[bq,k] . B_g[f,k]   M=1024 N=2048 K=Kg, split-K nsplit
    gemm_bt<<<dim3(16, 8, nsplit), 256, 0, stream>>>(
        A_g, B_g, Cpart,
        1024, 2048, (int)Kg,
        Kg, Kg, 2048, 1,
        0, 0, 0, 0, 0, 0,
        (g == 0) ? 2 : 3, (int)(Kg / nsplit), nullptr, 0);
  }

  // out[b,q,f] = fp32( sum_z Cpart + c0[f] + c1[f]*invln[bq] )
  k_out<<<2048, 256, 0, stream>>>(Cpart, c0, c1, invln, out, nsplit);
}

// Round 18
// 656.928 us; speedup vs baseline: 1.2816x; 1.0501x over previous
//
#include <hip/hip_runtime.h>
#include <hip/hip_bf16.h>
#include <stdint.h>

typedef __bf16 bf16;
typedef __bf16 bf16x8 __attribute__((ext_vector_type(8)));
typedef float f32x4 __attribute__((ext_vector_type(4)));

#define AS1 __attribute__((address_space(1)))
#define AS3 __attribute__((address_space(3)))

// B=4, S=256, H=12, DH=64(pad 128), D=768, FD=2048, FU=2048
// Inputs fp32 + int32 mask. OUTPUT fp32.
// R18: V-path refactor through DH: virtual = E1 (dot_k) G, where
// G[h,u,k] = sum_i updW^T[u,i] * W_V[h,i,k].  38.7G -> 8.9G MACs.

__device__ __forceinline__ void gld16(const bf16* g, bf16* l) {
  __builtin_amdgcn_global_load_lds((AS1 void*)g, (AS3 void*)l, 16, 0, 0);
}

__global__ void k_sentinel(float* __restrict__ out) {
  int i = blockIdx.x * 256 + threadIdx.x;
  if (i < 2097152) out[i] = 1048576.0f;
}

// ---------------- prep kernels ----------------

__global__ void k_invln(const float* __restrict__ ln, float* __restrict__ invln) {
  int i = blockIdx.x * 256 + threadIdx.x;
  if (i < 1024) invln[i] = 1.0f / ln[i];
}

__global__ void k_cast(const float* __restrict__ s, bf16* __restrict__ d, int n) {
  int i = blockIdx.x * 256 + threadIdx.x;
  if (i < n) d[i] = (bf16)s[i];
}

__global__ void k_WO(const float* __restrict__ W_O, bf16* __restrict__ WOb) {
  int i = blockIdx.x * 256 + threadIdx.x;           // 12*128*768
  int o = i % 768, r = (i / 768) & 127, h = i / (768 * 128);
  WOb[i] = (r < 64) ? (bf16)W_O[(long)(h * 64 + r) * 768 + o] : (bf16)0.0f;
}

__global__ void k_WV(const float* __restrict__ W_V, bf16* __restrict__ WVb) {
  int i = blockIdx.x * 256 + threadIdx.x;           // 12*768*128
  int k = i & 127, m = (i / 128) % 768, h = i / (128 * 768);
  WVb[i] = (k < 64) ? (bf16)W_V[(long)(h * 768 + m) * 64 + k] : (bf16)0.0f;
}

// WVt[h][k<128][i<768] = W_V[h,i,k], zero for k>=64
__global__ void k_WVt(const float* __restrict__ W_V, bf16* __restrict__ WVt) {
  int idx = blockIdx.x * 256 + threadIdx.x;         // 12*128*768
  int i768 = idx % 768, kk = (idx / 768) & 127, h = idx / (768 * 128);
  WVt[idx] = (kk < 64) ? (bf16)W_V[((long)(h * 768 + i768)) * 64 + kk] : (bf16)0.0f;
}

__global__ void k_updWt(const float* __restrict__ u, bf16* __restrict__ d) {
  int i = blockIdx.x * 256 + threadIdx.x;           // 2048*768
  int ii = i % 768, uu = i / 768;
  d[i] = (bf16)u[(long)ii * 2048 + uu];
}

__global__ void k_Xt(const float* __restrict__ resid, const float* __restrict__ invln,
                     bf16* __restrict__ Xt) {
  int i = blockIdx.x * 256 + threadIdx.x;           // 4*768*256
  int s = i & 255, d = (i >> 8) % 768, b = i / (768 * 256);
  int bs = b * 256 + s;
  Xt[i] = (bf16)(resid[(long)bs * 768 + d] * invln[bs]);
}

__global__ void k_Ut(const float* __restrict__ pr, const float* __restrict__ invln,
                     bf16* __restrict__ Ut) {
  int i = blockIdx.x * 256 + threadIdx.x;           // 4*2048*256
  int s = i & 255, u = (i >> 8) & 2047, b = i / (2048 * 256);
  int bs = b * 256 + s;
  Ut[i] = (bf16)(pr[(long)bs * 2048 + u] * invln[bs]);
}

// ---------------- bias chain (fp32, block-parallel) ----------------

__device__ __forceinline__ float blk_reduce(float s) {
  __shared__ float red[256];
  red[threadIdx.x] = s; __syncthreads();
  for (int o = 128; o > 0; o >>= 1) {
    if ((int)threadIdx.x < o) red[threadIdx.x] += red[threadIdx.x + o];
    __syncthreads();
  }
  float r = red[0]; __syncthreads();
  return r;
}

__global__ void k_bias_t(const float* __restrict__ W_V, const float* __restrict__ up_b,
                         float* __restrict__ t_hk) {
  int j = blockIdx.x, h = j >> 6, k = j & 63;
  float s = 0.f;
  for (int m = threadIdx.x; m < 768; m += 256)
    s += W_V[((long)(h * 768 + m)) * 64 + k] * up_b[m];
  float r = blk_reduce(s);
  if (threadIdx.x == 0) t_hk[j] = r;
}

__global__ void k_bias_w(const float* __restrict__ W_O, const float* __restrict__ t_hk,
                         float* __restrict__ w) {
  int d = blockIdx.x;
  float s = 0.f;
  for (int j = threadIdx.x; j < 768; j += 256)
    s += W_O[(long)j * 768 + d] * t_hk[j];
  float r = blk_reduce(s);
  if (threadIdx.x == 0) w[d] = r;
}

__global__ void k_bias_c(const float* __restrict__ enc_W, const float* __restrict__ enc_b,
                         const float* __restrict__ b_dec, const float* __restrict__ w,
                         float* __restrict__ c0, float* __restrict__ c1) {
  int f = blockIdx.x;
  float s0 = 0.f, s1 = 0.f;
  for (int d = threadIdx.x; d < 768; d += 256) {
    float e = enc_W[(long)f * 768 + d];
    s0 += e * b_dec[d];
    s1 += e * w[d];
  }
  float r0 = blk_reduce(s0);
  float r1 = blk_reduce(s1);
  if (threadIdx.x == 0) { c0[f] = enc_b[f] - r0; c1[f] = r1; }
}

// ---------------- GEMM (BT form: C[m,n] = sum_k A[m,k]*B[n,k]) ----------------
// BK=64, XOR-swizzled staging. K (and kChunk) must be multiples of 64.
// mode 0: bf16 store; mode 1: *= mask, bf16 store;
// mode 2: split-K fp32 overwrite; mode 3: split-K fp32 read-accumulate
__global__ __launch_bounds__(256)
void gemm_bt(const bf16* __restrict__ A, const bf16* __restrict__ B, void* __restrict__ Cv,
             int M, int N, int K,
             long lda, long ldb, long ldc,
             int batchH,
             long sa_b, long sa_h, long sb_b, long sb_h, long sc_b, long sc_h,
             int mode, int kChunk,
             const int* __restrict__ mask, long mask_ld)
{
  __shared__ __align__(16) bf16 Asm[128 * 64];
  __shared__ __align__(16) bf16 Bsm[128 * 64];

  const int t = threadIdx.x;
  const int m0 = blockIdx.y * 128;
  const int n0 = blockIdx.x * 128;

  long aoff, boff, coff;
  int k0, k1;
  if (mode >= 2) {
    int z = blockIdx.z;
    aoff = 0; boff = 0;
    coff = (long)z * (long)M * ldc;
    k0 = z * kChunk; k1 = k0 + kChunk; if (k1 > K) k1 = K;
  } else {
    int z = blockIdx.z;
    int bb = z / batchH, hh = z - bb * batchH;
    aoff = (long)bb * sa_b + (long)hh * sa_h;
    boff = (long)bb * sb_b + (long)hh * sb_h;
    coff = (long)bb * sc_b + (long)hh * sc_h;
    k0 = 0; k1 = K;
  }

  const bf16* Ab = A + aoff + (long)m0 * lda;
  const bf16* Bb = B + boff + (long)n0 * ldb;

  const int r0 = t >> 3;           // 0..31 (staging row within 32-row group)
  const int g8 = t & 7;            // staging col-group (LDS slot)

  const int L = t & 63, w = t >> 6;
  const int wm = (w & 1) * 64, wn = (w >> 1) * 64;
  const int r16 = L & 15, q = L >> 4;

  f32x4 acc[4][4];
#pragma unroll
  for (int i = 0; i < 4; i++)
#pragma unroll
    for (int j = 0; j < 4; j++) acc[i][j] = (f32x4){0.f, 0.f, 0.f, 0.f};

  for (int kt = k0; kt < k1; kt += 64) {
#pragma unroll
    for (int j = 0; j < 4; j++) {
      int row = j * 32 + r0;
      int sc = ((g8 ^ (row & 7)) << 3);      // source col swizzle
      gld16(Ab + (long)row * lda + (kt + sc), &Asm[j * 2048 + t * 8]);
      gld16(Bb + (long)row * ldb + (kt + sc), &Bsm[j * 2048 + t * 8]);
    }
    __syncthreads();

#pragma unroll
    for (int h2 = 0; h2 < 2; h2++) {
      bf16x8 af[4], bfr[4];
#pragma unroll
      for (int i = 0; i < 4; i++) {
        int ra = wm + i * 16 + r16;
        af[i]  = *(const bf16x8*)&Asm[ra * 64 + ((((h2 << 2) + q) ^ (ra & 7)) << 3)];
        int rb = wn + i * 16 + r16;
        bfr[i] = *(const bf16x8*)&Bsm[rb * 64 + ((((h2 << 2) + q) ^ (rb & 7)) << 3)];
      }
#pragma unroll
      for (int mi = 0; mi < 4; mi++)
#pragma unroll
        for (int ni = 0; ni < 4; ni++)
          acc[mi][ni] = __builtin_amdgcn_mfma_f32_16x16x32_bf16(af[mi], bfr[ni], acc[mi][ni], 0, 0, 0);
    }
    __syncthreads();
  }

  if (mode >= 2) {
    float* C = (float*)Cv;
#pragma unroll
    for (int mi = 0; mi < 4; mi++)
#pragma unroll
      for (int ni = 0; ni < 4; ni++)
#pragma unroll
        for (int r = 0; r < 4; r++) {
          int gm = m0 + wm + mi * 16 + q * 4 + r;
          int gn = n0 + wn + ni * 16 + r16;
          long idx = coff + (long)gm * ldc + gn;
          float v = acc[mi][ni][r];
          if (mode == 3) v += C[idx];
          C[idx] = v;
        }
  } else {
    bf16* C = (bf16*)Cv;
#pragma unroll
    for (int mi = 0; mi < 4; mi++)
#pragma unroll
      for (int ni = 0; ni < 4; ni++)
#pragma unroll
        for (int r = 0; r < 4; r++) {
          int gm = m0 + wm + mi * 16 + q * 4 + r;
          int gn = n0 + wn + ni * 16 + r16;
          float v = acc[mi][ni][r];
          if (mode == 1) v *= (float)mask[(long)gm * mask_ld + gn];
          C[coff + (long)gm * ldc + gn] = (bf16)v;
        }
  }
}

// ---------------- final reduce + bias epilogue (fp32 out, float4) ------------
__global__ void k_out(const float* __restrict__ Cp, const float* __restrict__ c0,
                      const float* __restrict__ c1, const float* __restrict__ invln,
                      float* __restrict__ out, int nsplit) {
  int i4 = blockIdx.x * 256 + threadIdx.x;          // 524288
  long i = (long)i4 * 4;
  int n = (int)(i & 2047), m = (int)(i >> 11);
  float4 v = *(const float4*)(Cp + i);
  for (int z = 1; z < nsplit; z++) {
    float4 u = *(const float4*)(Cp + i + (long)z * 2097152);
    v.x += u.x; v.y += u.y; v.z += u.z; v.w += u.w;
  }
  float il = invln[m];
  float4 a = *(const float4*)(c0 + n);
  float4 b = *(const float4*)(c1 + n);
  v.x += a.x + b.x * il;
  v.y += a.y + b.y * il;
  v.z += a.z + b.z * il;
  v.w += a.w + b.w * il;
  *(float4*)(out + i) = v;
}

// ---------------- host ----------------

extern "C" void kernel_launch(void* const* d_in, const int* in_sizes, int n_in,
                              void* d_out, int out_size, void* d_ws, size_t ws_size,
                              hipStream_t stream) {
  (void)out_size;
  float* out = (float*)d_out;

  // ---- resolve inputs by size (order-agnostic) ----
  int iresid = -1, iln = -1, iprobs = -1, iencb = -1, ipruned = -1, imask = -1;
  int iwo = -1, iwv = -1, iencw = -1, iupdw = -1, ibdec = -1, iupb = -1;
  for (int i = 0; i < n_in; i++) {
    switch (in_sizes[i]) {
      case 786432:  iresid  = i; break;
      case 1024:    iln     = i; break;
      case 3145728: iprobs  = i; break;
      case 2048:    iencb   = i; break;
      case 2097152: ipruned = i; break;
      case 4194304: imask   = i; break;
      case 589824:  if (iwo   < 0) iwo   = i; else iwv   = i; break;
      case 1572864: if (iencw < 0) iencw = i; else iupdw = i; break;
      case 768:     if (ibdec < 0) ibdec = i; else iupb  = i; break;
      default: break;
    }
  }
  bool ok = n_in == 12 && iresid >= 0 && iln >= 0 && iprobs >= 0 && iencb >= 0 &&
            ipruned >= 0 && imask >= 0 && iwo >= 0 && iwv >= 0 && iencw >= 0 &&
            iupdw >= 0 && ibdec >= 0 && iupb >= 0;
  if (!ok) { k_sentinel<<<8192, 256, 0, stream>>>(out); return; }

  const float* resid = (const float*)d_in[iresid];
  const float* lns   = (const float*)d_in[iln];
  const float* probs = (const float*)d_in[iprobs];
  const float* W_O   = (const float*)d_in[iwo];
  const float* W_V   = (const float*)d_in[iwv];
  const float* enc_W = (const float*)d_in[iencw];
  const float* enc_b = (const float*)d_in[iencb];
  const float* b_dec = (const float*)d_in[ibdec];
  const float* updW  = (const float*)d_in[iupdw];
  const float* up_b  = (const float*)d_in[iupb];
  const float* pruned= (const float*)d_in[ipruned];
  const int*   cmask = (const int*)d_in[imask];

  // ---- workspace config ----
  const size_t fixedB =
      2359296ull   // WOb
    + 2359296ull   // WVb
    + 2359296ull   // WVt
    + 6291456ull   // G_t
    + 3145728ull   // updWt
    + 1572864ull   // Xt
    + 4194304ull   // Ut
    + 6291456ull   // E1
    + 3145728ull   // encWb
    + 6291456ull   // probsb
    + 65536ull;
  auto abBytes = [](int g) -> size_t {
    return (size_t)1024 * g * 2816 * 2 + (size_t)2048 * g * 2816 * 2;
  };
  const size_t margin = 4ull << 20;
  const int cgs[9] = {12, 6, 6, 4, 3, 2, 2, 1, 1};
  const int cns[9] = { 8, 8, 4, 4, 4, 4, 2, 2, 1};
  int gs = 0, nsplit = 0;
  for (int ci = 0; ci < 9; ci++) {
    if (fixedB + (size_t)cns[ci] * 1024 * 2048 * 4 + abBytes(cgs[ci]) + margin <= ws_size) {
      gs = cgs[ci]; nsplit = cns[ci]; break;
    }
  }
  if (gs == 0) { gs = 1; nsplit = 1; }

  char* p = (char*)d_ws;
  auto alloc = [&](size_t bytes) -> char* {
    char* r = p; p += (bytes + 255) & ~(size_t)255; return r;
  };
  bf16*  WOb    = (bf16*)alloc(12ull * 128 * 768 * 2);
  bf16*  WVb    = (bf16*)alloc(12ull * 768 * 128 * 2);
  bf16*  WVt    = (bf16*)alloc(12ull * 128 * 768 * 2);
  bf16*  G_t    = (bf16*)alloc(12ull * 2048 * 128 * 2);
  bf16*  updWt  = (bf16*)alloc(2048ull * 768 * 2);
  bf16*  Xt     = (bf16*)alloc(4ull * 768 * 256 * 2);
  bf16*  Ut     = (bf16*)alloc(4ull * 2048 * 256 * 2);
  bf16*  E1     = (bf16*)alloc(12ull * 2048 * 128 * 2);
  bf16*  encWb  = (bf16*)alloc(2048ull * 768 * 2);
  bf16*  probsb = (bf16*)alloc(4ull * 12 * 256 * 256 * 2);
  float* invln  = (float*)alloc(1024 * 4);
  float* t_hk   = (float*)alloc(768 * 4);
  float* wv     = (float*)alloc(768 * 4);
  float* c0     = (float*)alloc(2048 * 4);
  float* c1     = (float*)alloc(2048 * 4);
  float* Cpart  = (float*)alloc((size_t)nsplit * 1024 * 2048 * 4);
  bf16*  A_g    = (bf16*)alloc((size_t)1024 * gs * 2816 * 2);
  bf16*  B_g    = (bf16*)alloc((size_t)2048 * gs * 2816 * 2);

  const long Kg = (long)gs * 2816;

  // ---- prep ----
  k_invln<<<4, 256, 0, stream>>>(lns, invln);
  k_cast<<<6144, 256, 0, stream>>>(enc_W, encWb, 1572864);
  k_cast<<<12288, 256, 0, stream>>>(probs, probsb, 3145728);
  k_WO<<<4608, 256, 0, stream>>>(W_O, WOb);
  k_WV<<<4608, 256, 0, stream>>>(W_V, WVb);
  k_WVt<<<4608, 256, 0, stream>>>(W_V, WVt);
  k_updWt<<<6144, 256, 0, stream>>>(updW, updWt);
  k_Xt<<<3072, 256, 0, stream>>>(resid, invln, Xt);
  k_Ut<<<8192, 256, 0, stream>>>(pruned, invln, Ut);
  k_bias_t<<<768, 256, 0, stream>>>(W_V, up_b, t_hk);
  k_bias_w<<<768, 256, 0, stream>>>(W_O, t_hk, wv);
  k_bias_c<<<2048, 256, 0, stream>>>(enc_W, enc_b, b_dec, wv, c0, c1);

  // E1[h][f][k128] = encWb[f,o] . WOb[h][k][o]   M=2048 N=128 K=768 (batched h)
  gemm_bt<<<dim3(1, 16, 12), 256, 0, stream>>>(
      encWb, WOb, E1, 2048, 128, 768,
      768, 768, 128, 12,
      0, 0, 0, (long)128 * 768, 0, (long)2048 * 128,
      0, 0, nullptr, 0);

  // G_t[h][u][k128] = updWt[u,i] . WVt[h][k][i]   M=2048 N=128 K=768 (batched h)
  gemm_bt<<<dim3(1, 16, 12), 256, 0, stream>>>(
      updWt, WVt, G_t, 2048, 128, 768,
      768, 768, 128, 12,
      0, 0, 0, (long)128 * 768, 0, (long)2048 * 128,
      0, 0, nullptr, 0);

  // ---- head-group loop ----
  for (int g = 0; g < 12 / gs; g++) {
    // M_g: B_g[f][hh*768 + i] = E1_h[f,k] . WVb_h[i,k]   M=2048 N=768 K=128
    gemm_bt<<<dim3(6, 16, gs), 256, 0, stream>>>(
        E1 + (long)g * gs * 2048 * 128, WVb + (long)g * gs * 768 * 128, B_g,
        2048, 768, 128,
        128, 128, Kg, gs,
        0, (long)2048 * 128, 0, (long)768 * 128, 0, 768,
        0, 0, nullptr, 0);

    // V_g: B_g[f][gs*768 + hh*2048 + u] = mask[f,u] * (E1_h[f,k] . G_t_h[u,k])  K=128
    gemm_bt<<<dim3(16, 16, gs), 256, 0, stream>>>(
        E1 + (long)g * gs * 2048 * 128, G_t + (long)g * gs * 2048 * 128, B_g + (long)gs * 768,
        2048, 2048, 128,
        128, 128, Kg, gs,
        0, (long)2048 * 128, 0, (long)2048 * 128, 0, 2048,
        1, 0, cmask, 2048);

    // PX_g: A_g[bq][hh*768 + i] = probsb[b,g*gs+hh][q,s] . Xt[b][i,s]  K=256
    gemm_bt<<<dim3(6, 2, 4 * gs), 256, 0, stream>>>(
        probsb + (long)g * gs * 65536, Xt, A_g,
        256, 768, 256,
        256, 256, Kg, gs,
        (long)12 * 65536, 65536, (long)768 * 256, 0, 256 * Kg, 768,
        0, 0, nullptr, 0);

    // PU_g: A_g[bq][gs*768 + hh*2048 + u] = probsb . Ut[b][u,s]  K=256
    gemm_bt<<<dim3(16, 2, 4 * gs), 256, 0, stream>>>(
        probsb + (long)g * gs * 65536, Ut, A_g + (long)gs * 768,
        256, 2048, 256,
        256, 256, Kg, gs,
        (long)12 * 65536, 65536, (long)2048 * 256, 0, 256 * Kg, 2048,
        0, 0, nullptr, 0);

    // Cpart (+)= A_g[bq,k] . B_g[f,k]   M=1024 N=2048 K=Kg, split-K nsplit
    gemm_bt<<<dim3(16, 8, nsplit), 256, 0, stream>>>(
        A_g, B_g, Cpart,
        1024, 2048, (int)Kg,
        Kg, Kg, 2048, 1,
        0, 0, 0, 0, 0, 0,
        (g == 0) ? 2 : 3, (int)(Kg / nsplit), nullptr, 0);
  }

  // out[b,q,f] = fp32( sum_z Cpart + c0[f] + c1[f]*invln[bq] )
  k_out<<<2048, 256, 0, stream>>>(Cpart, c0, c1, invln, out, nsplit);
}

// Round 19
// 599.507 us; speedup vs baseline: 1.4043x; 1.0958x over previous
//
#include <hip/hip_runtime.h>
#include <hip/hip_bf16.h>
#include <stdint.h>

typedef __bf16 bf16;
typedef __bf16 bf16x8 __attribute__((ext_vector_type(8)));
typedef float f32x4 __attribute__((ext_vector_type(4)));

#define AS1 __attribute__((address_space(1)))
#define AS3 __attribute__((address_space(3)))

// B=4, S=256, H=12, DH=64(pad 128), D=768, FD=2048, FU=2048
// Inputs fp32 + int32 mask. OUTPUT fp32.
// R19: final GEMM is HBM-bound (274 MB/dispatch) -> nsplit 8->4 halves C
// traffic; uncoalesced transpose preps -> LDS-tiled coalesced transposes.

__device__ __forceinline__ void gld16(const bf16* g, bf16* l) {
  __builtin_amdgcn_global_load_lds((AS1 void*)g, (AS3 void*)l, 16, 0, 0);
}

__global__ void k_sentinel(float* __restrict__ out) {
  int i = blockIdx.x * 256 + threadIdx.x;
  if (i < 2097152) out[i] = 1048576.0f;
}

// ---------------- prep kernels ----------------

__global__ void k_invln(const float* __restrict__ ln, float* __restrict__ invln) {
  int i = blockIdx.x * 256 + threadIdx.x;
  if (i < 1024) invln[i] = 1.0f / ln[i];
}

__global__ void k_cast(const float* __restrict__ s, bf16* __restrict__ d, int n) {
  int i = blockIdx.x * 256 + threadIdx.x;
  if (i < n) d[i] = (bf16)s[i];
}

__global__ void k_WO(const float* __restrict__ W_O, bf16* __restrict__ WOb) {
  int i = blockIdx.x * 256 + threadIdx.x;           // 12*128*768
  int o = i % 768, r = (i / 768) & 127, h = i / (768 * 128);
  WOb[i] = (r < 64) ? (bf16)W_O[(long)(h * 64 + r) * 768 + o] : (bf16)0.0f;
}

__global__ void k_WV(const float* __restrict__ W_V, bf16* __restrict__ WVb) {
  int i = blockIdx.x * 256 + threadIdx.x;           // 12*768*128
  int k = i & 127, m = (i / 128) % 768, h = i / (128 * 768);
  WVb[i] = (k < 64) ? (bf16)W_V[(long)(h * 768 + m) * 64 + k] : (bf16)0.0f;
}

// WVt[h][k<128][i<768] = W_V[h,i,k]  (tiled transpose, zero-pad k>=64)
__global__ void k_WVtT(const float* __restrict__ wv, bf16* __restrict__ WVt) {
  __shared__ float tile[32][33];
  int h = blockIdx.z;                 // 12
  int k0 = blockIdx.x * 32;           // 0..96
  int i0 = blockIdx.y * 32;           // 24 tiles
  int lane = threadIdx.x & 31, rg = threadIdx.x >> 5;
  if (k0 < 64) {
    for (int r = rg; r < 32; r += 8)
      tile[r][lane] = wv[((long)(h * 768 + i0 + r)) * 64 + k0 + lane];
    __syncthreads();
    for (int r = rg; r < 32; r += 8)
      WVt[((long)h * 128 + k0 + r) * 768 + i0 + lane] = (bf16)tile[lane][r];
  } else {
    for (int r = rg; r < 32; r += 8)
      WVt[((long)h * 128 + k0 + r) * 768 + i0 + lane] = (bf16)0.0f;
  }
}

// updWt[u][i] = up_dec_W[i][u]  (tiled transpose)
__global__ void k_updWtT(const float* __restrict__ u, bf16* __restrict__ d) {
  __shared__ float tile[32][33];
  int u0 = blockIdx.x * 32;           // 64 tiles
  int i0 = blockIdx.y * 32;           // 24 tiles
  int lane = threadIdx.x & 31, rg = threadIdx.x >> 5;
  for (int r = rg; r < 32; r += 8)
    tile[r][lane] = u[((long)(i0 + r)) * 2048 + u0 + lane];
  __syncthreads();
  for (int r = rg; r < 32; r += 8)
    d[((long)(u0 + r)) * 768 + i0 + lane] = (bf16)tile[lane][r];
}

// Xt[b][d][s] = resid[b,s,d] * invln  (tiled transpose)
__global__ void k_XtT(const float* __restrict__ resid, const float* __restrict__ invln,
                      bf16* __restrict__ Xt) {
  __shared__ float tile[32][33];
  int b = blockIdx.z, d0 = blockIdx.x * 32, s0 = blockIdx.y * 32;  // (24, 8, 4)
  int lane = threadIdx.x & 31, rg = threadIdx.x >> 5;
  for (int r = rg; r < 32; r += 8) {
    int s = s0 + r;
    tile[r][lane] = resid[((long)(b * 256 + s)) * 768 + d0 + lane] * invln[b * 256 + s];
  }
  __syncthreads();
  for (int r = rg; r < 32; r += 8)
    Xt[((long)b * 768 + d0 + r) * 256 + s0 + lane] = (bf16)tile[lane][r];
}

// Ut[b][u][s] = pruned[b,s,u] * invln  (tiled transpose)
__global__ void k_UtT(const float* __restrict__ pr, const float* __restrict__ invln,
                      bf16* __restrict__ Ut) {
  __shared__ float tile[32][33];
  int b = blockIdx.z, u0 = blockIdx.x * 32, s0 = blockIdx.y * 32;  // (64, 8, 4)
  int lane = threadIdx.x & 31, rg = threadIdx.x >> 5;
  for (int r = rg; r < 32; r += 8) {
    int s = s0 + r;
    tile[r][lane] = pr[((long)(b * 256 + s)) * 2048 + u0 + lane] * invln[b * 256 + s];
  }
  __syncthreads();
  for (int r = rg; r < 32; r += 8)
    Ut[((long)b * 2048 + u0 + r) * 256 + s0 + lane] = (bf16)tile[lane][r];
}

// ---------------- bias chain (fp32, block-parallel) ----------------

__device__ __forceinline__ float blk_reduce(float s) {
  __shared__ float red[256];
  red[threadIdx.x] = s; __syncthreads();
  for (int o = 128; o > 0; o >>= 1) {
    if ((int)threadIdx.x < o) red[threadIdx.x] += red[threadIdx.x + o];
    __syncthreads();
  }
  float r = red[0]; __syncthreads();
  return r;
}

__global__ void k_bias_t(const float* __restrict__ W_V, const float* __restrict__ up_b,
                         float* __restrict__ t_hk) {
  int j = blockIdx.x, h = j >> 6, k = j & 63;
  float s = 0.f;
  for (int m = threadIdx.x; m < 768; m += 256)
    s += W_V[((long)(h * 768 + m)) * 64 + k] * up_b[m];
  float r = blk_reduce(s);
  if (threadIdx.x == 0) t_hk[j] = r;
}

__global__ void k_bias_w(const float* __restrict__ W_O, const float* __restrict__ t_hk,
                         float* __restrict__ w) {
  int d = blockIdx.x;
  float s = 0.f;
  for (int j = threadIdx.x; j < 768; j += 256)
    s += W_O[(long)j * 768 + d] * t_hk[j];
  float r = blk_reduce(s);
  if (threadIdx.x == 0) w[d] = r;
}

__global__ void k_bias_c(const float* __restrict__ enc_W, const float* __restrict__ enc_b,
                         const float* __restrict__ b_dec, const float* __restrict__ w,
                         float* __restrict__ c0, float* __restrict__ c1) {
  int f = blockIdx.x;
  float s0 = 0.f, s1 = 0.f;
  for (int d = threadIdx.x; d < 768; d += 256) {
    float e = enc_W[(long)f * 768 + d];
    s0 += e * b_dec[d];
    s1 += e * w[d];
  }
  float r0 = blk_reduce(s0);
  float r1 = blk_reduce(s1);
  if (threadIdx.x == 0) { c0[f] = enc_b[f] - r0; c1[f] = r1; }
}

// ---------------- GEMM (BT form: C[m,n] = sum_k A[m,k]*B[n,k]) ----------------
// BK=64, XOR-swizzled staging. K (and kChunk) must be multiples of 64.
// mode 0: bf16 store; mode 1: *= mask, bf16 store;
// mode 2: split-K fp32 overwrite; mode 3: split-K fp32 read-accumulate
__global__ __launch_bounds__(256)
void gemm_bt(const bf16* __restrict__ A, const bf16* __restrict__ B, void* __restrict__ Cv,
             int M, int N, int K,
             long lda, long ldb, long ldc,
             int batchH,
             long sa_b, long sa_h, long sb_b, long sb_h, long sc_b, long sc_h,
             int mode, int kChunk,
             const int* __restrict__ mask, long mask_ld)
{
  __shared__ __align__(16) bf16 Asm[128 * 64];
  __shared__ __align__(16) bf16 Bsm[128 * 64];

  const int t = threadIdx.x;
  const int m0 = blockIdx.y * 128;
  const int n0 = blockIdx.x * 128;

  long aoff, boff, coff;
  int k0, k1;
  if (mode >= 2) {
    int z = blockIdx.z;
    aoff = 0; boff = 0;
    coff = (long)z * (long)M * ldc;
    k0 = z * kChunk; k1 = k0 + kChunk; if (k1 > K) k1 = K;
  } else {
    int z = blockIdx.z;
    int bb = z / batchH, hh = z - bb * batchH;
    aoff = (long)bb * sa_b + (long)hh * sa_h;
    boff = (long)bb * sb_b + (long)hh * sb_h;
    coff = (long)bb * sc_b + (long)hh * sc_h;
    k0 = 0; k1 = K;
  }

  const bf16* Ab = A + aoff + (long)m0 * lda;
  const bf16* Bb = B + boff + (long)n0 * ldb;

  const int r0 = t >> 3;           // 0..31 (staging row within 32-row group)
  const int g8 = t & 7;            // staging col-group (LDS slot)

  const int L = t & 63, w = t >> 6;
  const int wm = (w & 1) * 64, wn = (w >> 1) * 64;
  const int r16 = L & 15, q = L >> 4;

  f32x4 acc[4][4];
#pragma unroll
  for (int i = 0; i < 4; i++)
#pragma unroll
    for (int j = 0; j < 4; j++) acc[i][j] = (f32x4){0.f, 0.f, 0.f, 0.f};

  for (int kt = k0; kt < k1; kt += 64) {
#pragma unroll
    for (int j = 0; j < 4; j++) {
      int row = j * 32 + r0;
      int sc = ((g8 ^ (row & 7)) << 3);      // source col swizzle
      gld16(Ab + (long)row * lda + (kt + sc), &Asm[j * 2048 + t * 8]);
      gld16(Bb + (long)row * ldb + (kt + sc), &Bsm[j * 2048 + t * 8]);
    }
    __syncthreads();

#pragma unroll
    for (int h2 = 0; h2 < 2; h2++) {
      bf16x8 af[4], bfr[4];
#pragma unroll
      for (int i = 0; i < 4; i++) {
        int ra = wm + i * 16 + r16;
        af[i]  = *(const bf16x8*)&Asm[ra * 64 + ((((h2 << 2) + q) ^ (ra & 7)) << 3)];
        int rb = wn + i * 16 + r16;
        bfr[i] = *(const bf16x8*)&Bsm[rb * 64 + ((((h2 << 2) + q) ^ (rb & 7)) << 3)];
      }
#pragma unroll
      for (int mi = 0; mi < 4; mi++)
#pragma unroll
        for (int ni = 0; ni < 4; ni++)
          acc[mi][ni] = __builtin_amdgcn_mfma_f32_16x16x32_bf16(af[mi], bfr[ni], acc[mi][ni], 0, 0, 0);
    }
    __syncthreads();
  }

  if (mode >= 2) {
    float* C = (float*)Cv;
#pragma unroll
    for (int mi = 0; mi < 4; mi++)
#pragma unroll
      for (int ni = 0; ni < 4; ni++)
#pragma unroll
        for (int r = 0; r < 4; r++) {
          int gm = m0 + wm + mi * 16 + q * 4 + r;
          int gn = n0 + wn + ni * 16 + r16;
          long idx = coff + (long)gm * ldc + gn;
          float v = acc[mi][ni][r];
          if (mode == 3) v += C[idx];
          C[idx] = v;
        }
  } else {
    bf16* C = (bf16*)Cv;
#pragma unroll
    for (int mi = 0; mi < 4; mi++)
#pragma unroll
      for (int ni = 0; ni < 4; ni++)
#pragma unroll
        for (int r = 0; r < 4; r++) {
          int gm = m0 + wm + mi * 16 + q * 4 + r;
          int gn = n0 + wn + ni * 16 + r16;
          float v = acc[mi][ni][r];
          if (mode == 1) v *= (float)mask[(long)gm * mask_ld + gn];
          C[coff + (long)gm * ldc + gn] = (bf16)v;
        }
  }
}

// ---------------- final reduce + bias epilogue (fp32 out, float4) ------------
__global__ void k_out(const float* __restrict__ Cp, const float* __restrict__ c0,
                      const float* __restrict__ c1, const float* __restrict__ invln,
                      float* __restrict__ out, int nsplit) {
  int i4 = blockIdx.x * 256 + threadIdx.x;          // 524288
  long i = (long)i4 * 4;
  int n = (int)(i & 2047), m = (int)(i >> 11);
  float4 v = *(const float4*)(Cp + i);
  for (int z = 1; z < nsplit; z++) {
    float4 u = *(const float4*)(Cp + i + (long)z * 2097152);
    v.x += u.x; v.y += u.y; v.z += u.z; v.w += u.w;
  }
  float il = invln[m];
  float4 a = *(const float4*)(c0 + n);
  float4 b = *(const float4*)(c1 + n);
  v.x += a.x + b.x * il;
  v.y += a.y + b.y * il;
  v.z += a.z + b.z * il;
  v.w += a.w + b.w * il;
  *(float4*)(out + i) = v;
}

// ---------------- host ----------------

extern "C" void kernel_launch(void* const* d_in, const int* in_sizes, int n_in,
                              void* d_out, int out_size, void* d_ws, size_t ws_size,
                              hipStream_t stream) {
  (void)out_size;
  float* out = (float*)d_out;

  // ---- resolve inputs by size (order-agnostic) ----
  int iresid = -1, iln = -1, iprobs = -1, iencb = -1, ipruned = -1, imask = -1;
  int iwo = -1, iwv = -1, iencw = -1, iupdw = -1, ibdec = -1, iupb = -1;
  for (int i = 0; i < n_in; i++) {
    switch (in_sizes[i]) {
      case 786432:  iresid  = i; break;
      case 1024:    iln     = i; break;
      case 3145728: iprobs  = i; break;
      case 2048:    iencb   = i; break;
      case 2097152: ipruned = i; break;
      case 4194304: imask   = i; break;
      case 589824:  if (iwo   < 0) iwo   = i; else iwv   = i; break;
      case 1572864: if (iencw < 0) iencw = i; else iupdw = i; break;
      case 768:     if (ibdec < 0) ibdec = i; else iupb  = i; break;
      default: break;
    }
  }
  bool ok = n_in == 12 && iresid >= 0 && iln >= 0 && iprobs >= 0 && iencb >= 0 &&
            ipruned >= 0 && imask >= 0 && iwo >= 0 && iwv >= 0 && iencw >= 0 &&
            iupdw >= 0 && ibdec >= 0 && iupb >= 0;
  if (!ok) { k_sentinel<<<8192, 256, 0, stream>>>(out); return; }

  const float* resid = (const float*)d_in[iresid];
  const float* lns   = (const float*)d_in[iln];
  const float* probs = (const float*)d_in[iprobs];
  const float* W_O   = (const float*)d_in[iwo];
  const float* W_V   = (const float*)d_in[iwv];
  const float* enc_W = (const float*)d_in[iencw];
  const float* enc_b = (const float*)d_in[iencb];
  const float* b_dec = (const float*)d_in[ibdec];
  const float* updW  = (const float*)d_in[iupdw];
  const float* up_b  = (const float*)d_in[iupb];
  const float* pruned= (const float*)d_in[ipruned];
  const int*   cmask = (const int*)d_in[imask];

  // ---- workspace config ----
  const size_t fixedB =
      2359296ull   // WOb
    + 2359296ull   // WVb
    + 2359296ull   // WVt
    + 6291456ull   // G_t
    + 3145728ull   // updWt
    + 1572864ull   // Xt
    + 4194304ull   // Ut
    + 6291456ull   // E1
    + 3145728ull   // encWb
    + 6291456ull   // probsb
    + 65536ull;
  auto abBytes = [](int g) -> size_t {
    return (size_t)1024 * g * 2816 * 2 + (size_t)2048 * g * 2816 * 2;
  };
  const size_t margin = 4ull << 20;
  const int cgs[10] = {6, 6, 6, 4, 3, 2, 2, 1, 1, 1};
  const int cns[10] = {4, 8, 2, 4, 4, 4, 2, 4, 2, 1};
  int gs = 0, nsplit = 0;
  for (int ci = 0; ci < 10; ci++) {
    if (fixedB + (size_t)cns[ci] * 1024 * 2048 * 4 + abBytes(cgs[ci]) + margin <= ws_size) {
      gs = cgs[ci]; nsplit = cns[ci]; break;
    }
  }
  if (gs == 0) { gs = 1; nsplit = 1; }

  char* p = (char*)d_ws;
  auto alloc = [&](size_t bytes) -> char* {
    char* r = p; p += (bytes + 255) & ~(size_t)255; return r;
  };
  bf16*  WOb    = (bf16*)alloc(12ull * 128 * 768 * 2);
  bf16*  WVb    = (bf16*)alloc(12ull * 768 * 128 * 2);
  bf16*  WVt    = (bf16*)alloc(12ull * 128 * 768 * 2);
  bf16*  G_t    = (bf16*)alloc(12ull * 2048 * 128 * 2);
  bf16*  updWt  = (bf16*)alloc(2048ull * 768 * 2);
  bf16*  Xt     = (bf16*)alloc(4ull * 768 * 256 * 2);
  bf16*  Ut     = (bf16*)alloc(4ull * 2048 * 256 * 2);
  bf16*  E1     = (bf16*)alloc(12ull * 2048 * 128 * 2);
  bf16*  encWb  = (bf16*)alloc(2048ull * 768 * 2);
  bf16*  probsb = (bf16*)alloc(4ull * 12 * 256 * 256 * 2);
  float* invln  = (float*)alloc(1024 * 4);
  float* t_hk   = (float*)alloc(768 * 4);
  float* wv     = (float*)alloc(768 * 4);
  float* c0     = (float*)alloc(2048 * 4);
  float* c1     = (float*)alloc(2048 * 4);
  float* Cpart  = (float*)alloc((size_t)nsplit * 1024 * 2048 * 4);
  bf16*  A_g    = (bf16*)alloc((size_t)1024 * gs * 2816 * 2);
  bf16*  B_g    = (bf16*)alloc((size_t)2048 * gs * 2816 * 2);

  const long Kg = (long)gs * 2816;

  // ---- prep ----
  k_invln<<<4, 256, 0, stream>>>(lns, invln);
  k_cast<<<6144, 256, 0, stream>>>(enc_W, encWb, 1572864);
  k_cast<<<12288, 256, 0, stream>>>(probs, probsb, 3145728);
  k_WO<<<4608, 256, 0, stream>>>(W_O, WOb);
  k_WV<<<4608, 256, 0, stream>>>(W_V, WVb);
  k_WVtT<<<dim3(4, 24, 12), 256, 0, stream>>>(W_V, WVt);
  k_updWtT<<<dim3(64, 24), 256, 0, stream>>>(updW, updWt);
  k_XtT<<<dim3(24, 8, 4), 256, 0, stream>>>(resid, invln, Xt);
  k_UtT<<<dim3(64, 8, 4), 256, 0, stream>>>(pruned, invln, Ut);
  k_bias_t<<<768, 256, 0, stream>>>(W_V, up_b, t_hk);
  k_bias_w<<<768, 256, 0, stream>>>(W_O, t_hk, wv);
  k_bias_c<<<2048, 256, 0, stream>>>(enc_W, enc_b, b_dec, wv, c0, c1);

  // E1[h][f][k128] = encWb[f,o] . WOb[h][k][o]   M=2048 N=128 K=768 (batched h)
  gemm_bt<<<dim3(1, 16, 12), 256, 0, stream>>>(
      encWb, WOb, E1, 2048, 128, 768,
      768, 768, 128, 12,
      0, 0, 0, (long)128 * 768, 0, (long)2048 * 128,
      0, 0, nullptr, 0);

  // G_t[h][u][k128] = updWt[u,i] . WVt[h][k][i]   M=2048 N=128 K=768 (batched h)
  gemm_bt<<<dim3(1, 16, 12), 256, 0, stream>>>(
      updWt, WVt, G_t, 2048, 128, 768,
      768, 768, 128, 12,
      0, 0, 0, (long)128 * 768, 0, (long)2048 * 128,
      0, 0, nullptr, 0);

  // ---- head-group loop ----
  for (int g = 0; g < 12 / gs; g++) {
    // M_g: B_g[f][hh*768 + i] = E1_h[f,k] . WVb_h[i,k]   M=2048 N=768 K=128
    gemm_bt<<<dim3(6, 16, gs), 256, 0, stream>>>(
        E1 + (long)g * gs * 2048 * 128, WVb + (long)g * gs * 768 * 128, B_g,
        2048, 768, 128,
        128, 128, Kg, gs,
        0, (long)2048 * 128, 0, (long)768 * 128, 0, 768,
        0, 0, nullptr, 0);

    // V_g: B_g[f][gs*768 + hh*2048 + u] = mask[f,u] * (E1_h[f,k] . G_t_h[u,k])  K=128
    gemm_bt<<<dim3(16, 16, gs), 256, 0, stream>>>(
        E1 + (long)g * gs * 2048 * 128, G_t + (long)g * gs * 2048 * 128, B_g + (long)gs * 768,
        2048, 2048, 128,
        128, 128, Kg, gs,
        0, (long)2048 * 128, 0, (long)2048 * 128, 0, 2048,
        1, 0, cmask, 2048);

    // PX_g: A_g[bq][hh*768 + i] = probsb[b,g*gs+hh][q,s] . Xt[b][i,s]  K=256
    gemm_bt<<<dim3(6, 2, 4 * gs), 256, 0, stream>>>(
        probsb + (long)g * gs * 65536, Xt, A_g,
        256, 768, 256,
        256, 256, Kg, gs,
        (long)12 * 65536, 65536, (long)768 * 256, 0, 256 * Kg, 768,
        0, 0, nullptr, 0);

    // PU_g: A_g[bq][gs*768 + hh*2048 + u] = probsb . Ut[b][u,s]  K=256
    gemm_bt<<<dim3(16, 2, 4 * gs), 256, 0, stream>>>(
        probsb + (long)g * gs * 65536, Ut, A_g + (long)gs * 768,
        256, 2048, 256,
        256, 256, Kg, gs,
        (long)12 * 65536, 65536, (long)2048 * 256, 0, 256 * Kg, 2048,
        0, 0, nullptr, 0);

    // Cpart (+)= A_g[bq,k] . B_g[f,k]   M=1024 N=2048 K=Kg, split-K nsplit
    gemm_bt<<<dim3(16, 8, nsplit), 256, 0, stream>>>(
        A_g, B_g, Cpart,
        1024, 2048, (int)Kg,
        Kg, Kg, 2048, 1,
        0, 0, 0, 0, 0, 0,
        (g == 0) ? 2 : 3, (int)(Kg / nsplit), nullptr, 0);
  }

  // out[b,q,f] = fp32( sum_z Cpart + c0[f] + c1[f]*invln[bq] )
  k_out<<<2048, 256, 0, stream>>>(Cpart, c0, c1, invln, out, nsplit);
}